// Round 4
// baseline (441.097 us; speedup 1.0000x reference)
//
#include <hip/hip_runtime.h>
#include <math.h>

#define N_TOT 160000
#define NL0   100000
#define NL1   60000
#define NBOX  128
#define FMAXV 1e8f
#define CAP   2048

// ws float offsets
#define WS_SUM   0      // 128
#define WS_SQ    128    // 128
#define WS_S     256    // 128
#define WS_T     384    // 128
#define WS_T4    512    // 512 -> ends 1024
#define WS_WH    1024   // 1152 [k][j] -> ends 2176 (fallback epilogue)
#define WS_BH    2176   // 9
#define WS_KTH   2192   // 128 -> 2320
#define WS_TB    2320   // 128 -> 2448
#define WS_CNT   2448   // 128 ints -> 2576
#define WS_WHT   2576   // 1152 [j][k] -> ends 3728
#define WS_CAND  4096   // 128*2048 -> ends 266240
#define WS_FUSED 524288 // cached fused (160000*128 floats)

// ---------------- prep: zero stats/counters, init TB, T4, head weights (both layouts) ----------------
__global__ void prep_kernel(const float* __restrict__ text, const float* __restrict__ Wf,
                            const float* __restrict__ bfuse, const float* __restrict__ Wbbox,
                            const float* __restrict__ bbbox, const float* __restrict__ Wcls,
                            const float* __restrict__ bcls, float* __restrict__ ws)
{
    int t = threadIdx.x;
    if (t < 128) {
        ws[WS_SUM + t] = 0.f; ws[WS_SQ + t] = 0.f;
        ((int*)(ws + WS_CNT))[t] = 0;
        ((unsigned*)(ws + WS_TB))[t] = __float_as_uint(FMAXV);
    }
    for (int idx = t; idx < 512; idx += 256) {
        int b = idx >> 7, c = idx & 127;
        float acc = bfuse[c];
        for (int k = 0; k < 128; ++k) acc += text[b * 128 + k] * Wf[(128 + k) * 128 + c];
        ws[WS_T4 + idx] = acc;
    }
    for (int idx = t; idx < 1152; idx += 256) {
        int k = idx / 9, j = idx - k * 9;
        ws[WS_WH + idx] = (j < 7) ? Wbbox[k * 7 + j] : Wcls[k * 2 + (j - 7)];
    }
    for (int idx = t; idx < 1152; idx += 256) {
        int j = idx >> 7, k = idx & 127;
        ws[WS_WHT + idx] = (j < 7) ? Wbbox[k * 7 + j] : Wcls[k * 2 + (j - 7)];
    }
    if (t < 9) ws[WS_BH + t] = (t < 7) ? bbbox[t] : bcls[t - 7];
}

// ---------------- GEMM core: 64 rows/block, 4 phases x 32 K-rows staged in 16 KB LDS ----------------
#define GEMM_BODY4(A, Wf, lw, acc, r0, tx, ty, c0)                                       \
    for (int ph = 0; ph < 4; ++ph) {                                                     \
        const float4* wsrc = (const float4*)((Wf) + ph * 4096);                          \
        float4* wdst = (float4*)(lw);                                                    \
        for (int i = threadIdx.x; i < 1024; i += 256) wdst[i] = wsrc[i];                 \
        __syncthreads();                                                                 \
        for (int k4 = 0; k4 < 8; ++k4) {                                                 \
            float4 a[8];                                                                 \
            _Pragma("unroll")                                                            \
            for (int i = 0; i < 8; ++i)                                                  \
                a[i] = *(const float4*)((A) + (size_t)((r0) + (ty) * 8 + i) * 128 + ph * 32 + k4 * 4); \
            _Pragma("unroll")                                                            \
            for (int kk = 0; kk < 4; ++kk) {                                             \
                float4 w = *(const float4*)((lw) + (k4 * 4 + kk) * 128 + (c0));          \
                _Pragma("unroll")                                                        \
                for (int i = 0; i < 8; ++i) {                                            \
                    float av = (kk == 0) ? a[i].x : (kk == 1) ? a[i].y : (kk == 2) ? a[i].z : a[i].w; \
                    acc[i][0] += av * w.x; acc[i][1] += av * w.y;                        \
                    acc[i][2] += av * w.z; acc[i][3] += av * w.w;                        \
                }                                                                        \
            }                                                                            \
        }                                                                                \
        __syncthreads();                                                                 \
    }

__global__ __launch_bounds__(256) void gemm_stats_kernel(const float* __restrict__ A,
                                                         const float* __restrict__ Wf,
                                                         const int* __restrict__ bidx,
                                                         float* __restrict__ ws,
                                                         float* __restrict__ fused_out)
{
    __shared__ float lw[4096];
    __shared__ float red[2048];
    const int tid = threadIdx.x;
    const int tx = tid & 31, ty = tid >> 5;
    const int r0 = blockIdx.x * 64;
    const int c0 = tx * 4;
    float acc[8][4];
#pragma unroll
    for (int i = 0; i < 8; ++i)
#pragma unroll
        for (int j = 0; j < 4; ++j) acc[i][j] = 0.f;

    GEMM_BODY4(A, Wf, lw, acc, r0, tx, ty, c0)

    const float* T4 = ws + WS_T4;
#pragma unroll
    for (int i = 0; i < 8; ++i) {
        int r = r0 + ty * 8 + i;
        int b = bidx[r];
        float4 tv = *(const float4*)(T4 + b * 128 + c0);
        acc[i][0] += tv.x; acc[i][1] += tv.y; acc[i][2] += tv.z; acc[i][3] += tv.w;
    }
    if (fused_out) {
#pragma unroll
        for (int i = 0; i < 8; ++i) {
            int r = r0 + ty * 8 + i;
            *(float4*)(fused_out + (size_t)r * 128 + c0) =
                make_float4(acc[i][0], acc[i][1], acc[i][2], acc[i][3]);
        }
    }
    // stats: contiguous float4 stores (conflict-free), layout red[ty][c]
    {
        float s[4], q[4];
#pragma unroll
        for (int j = 0; j < 4; ++j) {
            float a0 = 0.f, a1 = 0.f;
#pragma unroll
            for (int i = 0; i < 8; ++i) { float v = acc[i][j]; a0 += v; a1 += v * v; }
            s[j] = a0; q[j] = a1;
        }
        *(float4*)(red + ty * 128 + c0)        = make_float4(s[0], s[1], s[2], s[3]);
        *(float4*)(red + 1024 + ty * 128 + c0) = make_float4(q[0], q[1], q[2], q[3]);
    }
    __syncthreads();
    if (tid < 128) {
        float s = 0.f, s2 = 0.f;
#pragma unroll
        for (int u = 0; u < 8; ++u) { s += red[u * 128 + tid]; s2 += red[1024 + u * 128 + tid]; }
        atomicAdd(ws + WS_SUM + tid, s);
        atomicAdd(ws + WS_SQ + tid, s2);
    }
}

__global__ void finalize_kernel(const float* __restrict__ gamma, const float* __restrict__ beta,
                                float* __restrict__ ws, int n)
{
    int c = threadIdx.x;
    if (c < 128) {
        float inv_n = 1.f / (float)n;
        float mu  = ws[WS_SUM + c] * inv_n;
        float var = ws[WS_SQ + c] * inv_n - mu * mu;
        float s = gamma[c] / sqrtf(var + 1e-5f);
        ws[WS_S + c] = s;
        ws[WS_T + c] = beta[c] - mu * s;
    }
}

// ---------------- heads: one thread per row, no LDS, no shuffles ----------------
__global__ __launch_bounds__(256) void heads_rows_kernel(const float* __restrict__ fused,
                                                         const float* __restrict__ ws,
                                                         float* __restrict__ out)
{
    int r = blockIdx.x * 256 + threadIdx.x;
    if (r >= N_TOT) return;
    const float4* xr = (const float4*)(fused + (size_t)r * 128);
    const float4* s4 = (const float4*)(ws + WS_S);
    const float4* t4 = (const float4*)(ws + WS_T);
    float4 x[32];
#pragma unroll
    for (int k = 0; k < 32; ++k) {
        float4 v = xr[k];
        float4 s = s4[k], t = t4[k];
        x[k].x = fmaxf(v.x * s.x + t.x, 0.f);
        x[k].y = fmaxf(v.y * s.y + t.y, 0.f);
        x[k].z = fmaxf(v.z * s.z + t.z, 0.f);
        x[k].w = fmaxf(v.w * s.w + t.w, 0.f);
    }
    float p[9];
#pragma unroll
    for (int j = 0; j < 9; ++j) {
        const float4* wj = (const float4*)(ws + WS_WHT + j * 128);
        float ax = 0.f, ay = 0.f, az = 0.f, aw = 0.f;
#pragma unroll
        for (int k = 0; k < 32; ++k) {
            float4 w = wj[k];
            ax += x[k].x * w.x; ay += x[k].y * w.y;
            az += x[k].z * w.z; aw += x[k].w * w.w;
        }
        p[j] = (ax + ay) + (az + aw) + ws[WS_BH + j];
    }
    float* o = out + (size_t)r * 9;
    o[0] = p[0]; o[1] = p[1]; o[2] = p[2];
    o[3] = expf(p[3]); o[4] = expf(p[4]); o[5] = expf(p[5]);
    o[6] = p[6]; o[7] = p[7]; o[8] = p[8];
}

// -------- fallback epilogue (ws too small for fused cache) --------
__device__ __forceinline__ void heads_epilogue(float acc[8][4], const float* __restrict__ ws,
                                               float* __restrict__ out, int r0, int tx, int ty, int c0)
{
    float4 sc = *(const float4*)(ws + WS_S + c0);
    float4 tb = *(const float4*)(ws + WS_T + c0);
#pragma unroll
    for (int i = 0; i < 8; ++i) {
        acc[i][0] = fmaxf(acc[i][0] * sc.x + tb.x, 0.f);
        acc[i][1] = fmaxf(acc[i][1] * sc.y + tb.y, 0.f);
        acc[i][2] = fmaxf(acc[i][2] * sc.z + tb.z, 0.f);
        acc[i][3] = fmaxf(acc[i][3] * sc.w + tb.w, 0.f);
    }
    float wh[4][9];
#pragma unroll
    for (int jj = 0; jj < 4; ++jj)
#pragma unroll
        for (int j = 0; j < 9; ++j) wh[jj][j] = ws[WS_WH + (c0 + jj) * 9 + j];
    float bh[9];
#pragma unroll
    for (int j = 0; j < 9; ++j) bh[j] = ws[WS_BH + j];

#pragma unroll
    for (int i = 0; i < 8; ++i) {
        float p[9];
#pragma unroll
        for (int j = 0; j < 9; ++j) p[j] = 0.f;
#pragma unroll
        for (int jj = 0; jj < 4; ++jj) {
            float xv = acc[i][jj];
#pragma unroll
            for (int j = 0; j < 9; ++j) p[j] += xv * wh[jj][j];
        }
#pragma unroll
        for (int m = 1; m <= 16; m <<= 1)
#pragma unroll
            for (int j = 0; j < 9; ++j) p[j] += __shfl_xor(p[j], m);
        if (tx == 0) {
            int r = r0 + ty * 8 + i;
            float* o = out + (size_t)r * 9;
            o[0] = p[0] + bh[0];
            o[1] = p[1] + bh[1];
            o[2] = p[2] + bh[2];
            o[3] = expf(p[3] + bh[3]);
            o[4] = expf(p[4] + bh[4]);
            o[5] = expf(p[5] + bh[5]);
            o[6] = p[6] + bh[6];
            o[7] = p[7] + bh[7];
            o[8] = p[8] + bh[8];
        }
    }
}

__global__ __launch_bounds__(256) void heads_kernel(const float* __restrict__ A,
                                                    const float* __restrict__ Wf,
                                                    const int* __restrict__ bidx,
                                                    const float* __restrict__ ws,
                                                    float* __restrict__ out)
{
    __shared__ float lw[4096];
    const int tid = threadIdx.x;
    const int tx = tid & 31, ty = tid >> 5;
    const int r0 = blockIdx.x * 64;
    const int c0 = tx * 4;
    float acc[8][4];
#pragma unroll
    for (int i = 0; i < 8; ++i)
#pragma unroll
        for (int j = 0; j < 4; ++j) acc[i][j] = 0.f;

    GEMM_BODY4(A, Wf, lw, acc, r0, tx, ty, c0)

    const float* T4 = ws + WS_T4;
#pragma unroll
    for (int i = 0; i < 8; ++i) {
        int r = r0 + ty * 8 + i;
        int b = bidx[r];
        float4 tv = *(const float4*)(T4 + b * 128 + c0);
        acc[i][0] += tv.x; acc[i][1] += tv.y; acc[i][2] += tv.z; acc[i][3] += tv.w;
    }
    heads_epilogue(acc, ws, out, r0, tx, ty, c0);
}

// ---------------- kth phase 1: sliced bound, atomicMin combine ----------------
// T_j = min over slices of (33rd smallest of the slice's 256 thread-minima).
// The argmin slice has >=33 distinct points <= T_j, so T_j >= true 33rd smallest.
__global__ __launch_bounds__(256) void bound_kernel(const float* __restrict__ p0,
                                                    const float* __restrict__ p1,
                                                    const float* __restrict__ boxes,
                                                    const int* __restrict__ glabels,
                                                    float* __restrict__ ws)
{
    const int j = blockIdx.x;
    const int slice = blockIdx.y, nslice = gridDim.y;
    const int tid = threadIdx.x;
    const float cx = boxes[j * 7 + 0], cy = boxes[j * 7 + 1], cz = boxes[j * 7 + 2];
    const int lvl = glabels[j];
    const float* pts = (lvl == 0) ? p0 : p1;
    const int M = (lvl == 0) ? NL0 : NL1;

    const int chunk = (M + nslice - 1) / nslice;
    const int i0 = slice * chunk;
    const int i1 = min(M, i0 + chunk);

    float m = FMAXV;
    for (int i = i0 + tid; i < i1; i += 256) {
        float dx = __fsub_rn(pts[i * 3 + 0], cx);
        float dy = __fsub_rn(pts[i * 3 + 1], cy);
        float dz = __fsub_rn(pts[i * 3 + 2], cz);
        float d2 = __fadd_rn(__fadd_rn(__fmul_rn(dx, dx), __fmul_rn(dy, dy)), __fmul_rn(dz, dz));
        m = fminf(m, d2);
    }

    __shared__ int wsum[4];
    unsigned lo = 0u, hi = __float_as_uint(FMAXV);
    for (int it = 0; it < 32; ++it) {
        unsigned mid = lo + ((hi - lo) >> 1);
        float midf = __uint_as_float(mid);
        unsigned long long b = __ballot(m <= midf);
        if ((tid & 63) == 0) wsum[tid >> 6] = __popcll(b);
        __syncthreads();
        int total = wsum[0] + wsum[1] + wsum[2] + wsum[3];
        if (total >= 33) hi = mid; else lo = mid + 1;
        __syncthreads();
    }
    if (tid == 0) atomicMin((unsigned*)(ws + WS_TB) + j, hi);
}

// ---------------- kth phase 2: collect ALL d2 <= T_j per box ----------------
__global__ __launch_bounds__(256) void collect_kernel(const float* __restrict__ p0,
                                                      const float* __restrict__ p1,
                                                      const float* __restrict__ boxes,
                                                      const int* __restrict__ glabels,
                                                      float* __restrict__ ws)
{
    const int j = blockIdx.x;
    const int slice = blockIdx.y, nslice = gridDim.y;
    const int tid = threadIdx.x;
    const float cx = boxes[j * 7 + 0], cy = boxes[j * 7 + 1], cz = boxes[j * 7 + 2];
    const int lvl = glabels[j];
    const float* pts = (lvl == 0) ? p0 : p1;
    const int M = (lvl == 0) ? NL0 : NL1;
    const float T = ws[WS_TB + j];
    int* cnt = (int*)(ws + WS_CNT) + j;
    float* cand = ws + WS_CAND + (size_t)j * CAP;

    const int chunk = (M + nslice - 1) / nslice;
    const int i0 = slice * chunk;
    const int i1 = min(M, i0 + chunk);
    for (int i = i0 + tid; i < i1; i += 256) {
        float dx = __fsub_rn(pts[i * 3 + 0], cx);
        float dy = __fsub_rn(pts[i * 3 + 1], cy);
        float dz = __fsub_rn(pts[i * 3 + 2], cz);
        float d2 = __fadd_rn(__fadd_rn(__fmul_rn(dx, dx), __fmul_rn(dy, dy)), __fmul_rn(dz, dz));
        if (d2 <= T) {
            int idx = atomicAdd(cnt, 1);
            if (idx < CAP) cand[idx] = d2;
        }
    }
}

// ---------------- kth phase 3: exact rank-33 over collected candidates ----------------
__global__ __launch_bounds__(256) void select_kernel(float* __restrict__ ws)
{
    const int j = blockIdx.x;
    const int tid = threadIdx.x;
    int n = ((int*)(ws + WS_CNT))[j];
    if (n > CAP) n = CAP;
    const float* cand = ws + WS_CAND + (size_t)j * CAP;
    float v[CAP / 256];
#pragma unroll
    for (int u = 0; u < CAP / 256; ++u) {
        int t = tid + u * 256;
        v[u] = (t < n) ? cand[t] : FMAXV;
    }
    __shared__ int wsum[4];
    unsigned lo = 0u, hi = __float_as_uint(FMAXV);
    for (int it = 0; it < 32; ++it) {
        unsigned mid = lo + ((hi - lo) >> 1);
        float midf = __uint_as_float(mid);
        int c = 0;
#pragma unroll
        for (int u = 0; u < CAP / 256; ++u) c += (v[u] <= midf) ? 1 : 0;
#pragma unroll
        for (int m = 32; m >= 1; m >>= 1) c += __shfl_xor(c, m);
        if ((tid & 63) == 0) wsum[tid >> 6] = c;
        __syncthreads();
        int total = wsum[0] + wsum[1] + wsum[2] + wsum[3];
        if (total >= 33) hi = mid; else lo = mid + 1;
        __syncthreads();
    }
    if (tid == 0) ws[WS_KTH + j] = __uint_as_float(hi);
}

// ---------------- assign: per point, raw argmin + gated argmin ----------------
__global__ __launch_bounds__(256) void assign_kernel(const float* __restrict__ p0,
                                                     const float* __restrict__ p1,
                                                     const float* __restrict__ boxes,
                                                     const int* __restrict__ glabels,
                                                     const float* __restrict__ ws,
                                                     float* __restrict__ out)
{
    __shared__ float cxa[128], cya[128], cza[128], kva[128];
    __shared__ int lva[128];
    int tid = threadIdx.x;
    if (tid < 128) {
        cxa[tid] = boxes[tid * 7 + 0];
        cya[tid] = boxes[tid * 7 + 1];
        cza[tid] = boxes[tid * 7 + 2];
        kva[tid] = ws[WS_KTH + tid];
        lva[tid] = glabels[tid];
    }
    __syncthreads();
    int i = blockIdx.x * 256 + tid;
    if (i >= N_TOT) return;
    int lvl = (i < NL0) ? 0 : 1;
    const float* p = (lvl == 0) ? (p0 + (size_t)i * 3) : (p1 + (size_t)(i - NL0) * 3);
    float px = p[0], py = p[1], pz = p[2];
    float bestA = FMAXV; int jA = 0;
    float bestG = FMAXV; int jG = -1;
    for (int j = 0; j < 128; ++j) {
        float dx = __fsub_rn(px, cxa[j]);
        float dy = __fsub_rn(py, cya[j]);
        float dz = __fsub_rn(pz, cza[j]);
        float d2 = __fadd_rn(__fadd_rn(__fmul_rn(dx, dx), __fmul_rn(dy, dy)), __fmul_rn(dz, dz));
        if (d2 < bestA) { bestA = d2; jA = j; }
        bool ok = (lva[j] == lvl) && (d2 < kva[j]);
        if (ok && d2 < bestG) { bestG = d2; jG = j; }
    }
    int res = (jG >= 0 && jG == jA) ? jG : -1;
    out[(size_t)9 * N_TOT + i] = (float)res;
}

extern "C" void kernel_launch(void* const* d_in, const int* in_sizes, int n_in,
                              void* d_out, int out_size, void* d_ws, size_t ws_size,
                              hipStream_t stream)
{
    const float* backbone = (const float*)d_in[0];
    const float* text     = (const float*)d_in[1];
    const float* Wf       = (const float*)d_in[2];
    const float* bfuse    = (const float*)d_in[3];
    const float* gamma    = (const float*)d_in[4];
    const float* beta     = (const float*)d_in[5];
    const float* Wbbox    = (const float*)d_in[6];
    const float* bbbox    = (const float*)d_in[7];
    const float* Wcls     = (const float*)d_in[8];
    const float* bcls     = (const float*)d_in[9];
    const float* p0       = (const float*)d_in[10];
    const float* p1       = (const float*)d_in[11];
    const int*   bidx     = (const int*)d_in[12];
    const int*   glab     = (const int*)d_in[13];
    const float* boxes    = (const float*)d_in[14];
    float* out = (float*)d_out;
    float* ws  = (float*)d_ws;

    const size_t need = ((size_t)WS_FUSED + (size_t)N_TOT * 128) * sizeof(float);
    const bool cache_fused = (ws_size >= need);
    float* fused = cache_fused ? (ws + WS_FUSED) : nullptr;

    prep_kernel<<<1, 256, 0, stream>>>(text, Wf, bfuse, Wbbox, bbbox, Wcls, bcls, ws);
    bound_kernel<<<dim3(NBOX, 8), 256, 0, stream>>>(p0, p1, boxes, glab, ws);
    collect_kernel<<<dim3(NBOX, 8), 256, 0, stream>>>(p0, p1, boxes, glab, ws);
    select_kernel<<<NBOX, 256, 0, stream>>>(ws);
    gemm_stats_kernel<<<N_TOT / 64, 256, 0, stream>>>(backbone, Wf, bidx, ws, fused);
    finalize_kernel<<<1, 128, 0, stream>>>(gamma, beta, ws, N_TOT);
    if (cache_fused)
        heads_rows_kernel<<<(N_TOT + 255) / 256, 256, 0, stream>>>(fused, ws, out);
    else
        heads_kernel<<<N_TOT / 64, 256, 0, stream>>>(backbone, Wf, bidx, ws, out);
    assign_kernel<<<(N_TOT + 255) / 256, 256, 0, stream>>>(p0, p1, boxes, glab, ws, out);
}

// Round 5
// 409.296 us; speedup vs baseline: 1.0777x; 1.0777x over previous
//
#include <hip/hip_runtime.h>
#include <math.h>

#define N_TOT 160000
#define NL0   100000
#define NL1   60000
#define NBOX  128
#define FMAXV 1e8f
#define CAP   2048

// ws float offsets
#define WS_SUM   0      // 128
#define WS_SQ    128    // 128
#define WS_S     256    // 128
#define WS_T     384    // 128
#define WS_T4    512    // 512 -> ends 1024
#define WS_WH    1024   // 1152 [k][j] -> ends 2176
#define WS_BH    2176   // 9
#define WS_KTH   2192   // 128 -> 2320
#define WS_TB    2320   // 128 -> 2448
#define WS_CNT   2448   // 128 ints -> 2576
#define WS_CAND  4096   // 128*2048 -> ends 266240
#define WS_FUSED 524288 // cached fused (160000*128 floats)

// ---------------- prep_t4: T4 = text@Wf[128:]+b_fuse (512 threads, one dot each) ----------------
__global__ __launch_bounds__(512) void prep_t4_kernel(const float* __restrict__ text,
                                                      const float* __restrict__ Wf,
                                                      const float* __restrict__ bfuse,
                                                      float* __restrict__ ws)
{
    int idx = threadIdx.x;            // 512 = 4 batches x 128 cols
    int b = idx >> 7, c = idx & 127;
    float acc = bfuse[c];
    for (int k = 0; k < 128; ++k)
        acc += text[b * 128 + k] * Wf[(128 + k) * 128 + c];
    ws[WS_T4 + idx] = acc;
}

// ---------------- prep_misc: zero stats/counters, init TB, pack head weights ----------------
__global__ void prep_misc_kernel(const float* __restrict__ Wbbox, const float* __restrict__ bbbox,
                                 const float* __restrict__ Wcls, const float* __restrict__ bcls,
                                 float* __restrict__ ws)
{
    int t = threadIdx.x;
    if (t < 128) {
        ws[WS_SUM + t] = 0.f; ws[WS_SQ + t] = 0.f;
        ((int*)(ws + WS_CNT))[t] = 0;
        ((unsigned*)(ws + WS_TB))[t] = __float_as_uint(FMAXV);
    }
    for (int idx = t; idx < 1152; idx += 256) {
        int k = idx / 9, j = idx - k * 9;
        ws[WS_WH + idx] = (j < 7) ? Wbbox[k * 7 + j] : Wcls[k * 2 + (j - 7)];
    }
    if (t < 9) ws[WS_BH + t] = (t < 7) ? bbbox[t] : bcls[t - 7];
}

// ---------------- GEMM core: 64 rows/block, 2 phases x 64 K-rows in 32 KB LDS,
// ---------------- register double-buffered A loads ----------------
#define GEMM_BODY(A, Wf, lw, acc, r0, tx, ty, c0)                                        \
    for (int ph = 0; ph < 2; ++ph) {                                                     \
        const float4* wsrc = (const float4*)((Wf) + ph * 8192);                          \
        float4* wdst = (float4*)(lw);                                                    \
        for (int i = threadIdx.x; i < 2048; i += 256) wdst[i] = wsrc[i];                 \
        __syncthreads();                                                                 \
        const float* abase = (A) + (size_t)((r0) + (ty) * 8) * 128 + ph * 64;            \
        float4 acur[8], anxt[8];                                                         \
        _Pragma("unroll")                                                                \
        for (int i = 0; i < 8; ++i) acur[i] = *(const float4*)(abase + (size_t)i * 128); \
        for (int k4 = 0; k4 < 16; ++k4) {                                                \
            if (k4 < 15) {                                                               \
                _Pragma("unroll")                                                        \
                for (int i = 0; i < 8; ++i)                                              \
                    anxt[i] = *(const float4*)(abase + (size_t)i * 128 + (k4 + 1) * 4);  \
            }                                                                            \
            _Pragma("unroll")                                                            \
            for (int kk = 0; kk < 4; ++kk) {                                             \
                float4 w = *(const float4*)((lw) + (k4 * 4 + kk) * 128 + (c0));          \
                _Pragma("unroll")                                                        \
                for (int i = 0; i < 8; ++i) {                                            \
                    float av = (kk == 0) ? acur[i].x : (kk == 1) ? acur[i].y :           \
                               (kk == 2) ? acur[i].z : acur[i].w;                        \
                    acc[i][0] += av * w.x; acc[i][1] += av * w.y;                        \
                    acc[i][2] += av * w.z; acc[i][3] += av * w.w;                        \
                }                                                                        \
            }                                                                            \
            _Pragma("unroll")                                                            \
            for (int i = 0; i < 8; ++i) acur[i] = anxt[i];                               \
        }                                                                                \
        __syncthreads();                                                                 \
    }

__global__ __launch_bounds__(256) void gemm_stats_kernel(const float* __restrict__ A,
                                                         const float* __restrict__ Wf,
                                                         const int* __restrict__ bidx,
                                                         float* __restrict__ ws,
                                                         float* __restrict__ fused_out)
{
    __shared__ float lw[8192];
    __shared__ float red[2048];
    const int tid = threadIdx.x;
    const int tx = tid & 31, ty = tid >> 5;
    const int r0 = blockIdx.x * 64;
    const int c0 = tx * 4;
    float acc[8][4];
#pragma unroll
    for (int i = 0; i < 8; ++i)
#pragma unroll
        for (int j = 0; j < 4; ++j) acc[i][j] = 0.f;

    GEMM_BODY(A, Wf, lw, acc, r0, tx, ty, c0)

    const float* T4 = ws + WS_T4;
#pragma unroll
    for (int i = 0; i < 8; ++i) {
        int r = r0 + ty * 8 + i;
        int b = bidx[r];
        float4 tv = *(const float4*)(T4 + b * 128 + c0);
        acc[i][0] += tv.x; acc[i][1] += tv.y; acc[i][2] += tv.z; acc[i][3] += tv.w;
    }
    if (fused_out) {
#pragma unroll
        for (int i = 0; i < 8; ++i) {
            int r = r0 + ty * 8 + i;
            *(float4*)(fused_out + (size_t)r * 128 + c0) =
                make_float4(acc[i][0], acc[i][1], acc[i][2], acc[i][3]);
        }
    }
    // stats: contiguous float4 stores (conflict-free), layout red[ty][c]
    {
        float s[4], q[4];
#pragma unroll
        for (int j = 0; j < 4; ++j) {
            float a0 = 0.f, a1 = 0.f;
#pragma unroll
            for (int i = 0; i < 8; ++i) { float v = acc[i][j]; a0 += v; a1 += v * v; }
            s[j] = a0; q[j] = a1;
        }
        *(float4*)(red + ty * 128 + c0)        = make_float4(s[0], s[1], s[2], s[3]);
        *(float4*)(red + 1024 + ty * 128 + c0) = make_float4(q[0], q[1], q[2], q[3]);
    }
    __syncthreads();
    if (tid < 128) {
        float s = 0.f, s2 = 0.f;
#pragma unroll
        for (int u = 0; u < 8; ++u) { s += red[u * 128 + tid]; s2 += red[1024 + u * 128 + tid]; }
        atomicAdd(ws + WS_SUM + tid, s);
        atomicAdd(ws + WS_SQ + tid, s2);
    }
}

__global__ void finalize_kernel(const float* __restrict__ gamma, const float* __restrict__ beta,
                                float* __restrict__ ws, int n)
{
    int c = threadIdx.x;
    if (c < 128) {
        float inv_n = 1.f / (float)n;
        float mu  = ws[WS_SUM + c] * inv_n;
        float var = ws[WS_SQ + c] * inv_n - mu * mu;
        float s = gamma[c] / sqrtf(var + 1e-5f);
        ws[WS_S + c] = s;
        ws[WS_T + c] = beta[c] - mu * s;
    }
}

// -------- epilogue: BN+ReLU, 9-col head matvec, shuffle-reduce, write out --------
__device__ __forceinline__ void heads_epilogue(float acc[8][4], const float* __restrict__ ws,
                                               float* __restrict__ out, int r0, int tx, int ty, int c0)
{
    float4 sc = *(const float4*)(ws + WS_S + c0);
    float4 tb = *(const float4*)(ws + WS_T + c0);
#pragma unroll
    for (int i = 0; i < 8; ++i) {
        acc[i][0] = fmaxf(acc[i][0] * sc.x + tb.x, 0.f);
        acc[i][1] = fmaxf(acc[i][1] * sc.y + tb.y, 0.f);
        acc[i][2] = fmaxf(acc[i][2] * sc.z + tb.z, 0.f);
        acc[i][3] = fmaxf(acc[i][3] * sc.w + tb.w, 0.f);
    }
    float wh[4][9];
#pragma unroll
    for (int jj = 0; jj < 4; ++jj)
#pragma unroll
        for (int j = 0; j < 9; ++j) wh[jj][j] = ws[WS_WH + (c0 + jj) * 9 + j];
    float bh[9];
#pragma unroll
    for (int j = 0; j < 9; ++j) bh[j] = ws[WS_BH + j];

#pragma unroll
    for (int i = 0; i < 8; ++i) {
        float p[9];
#pragma unroll
        for (int j = 0; j < 9; ++j) p[j] = 0.f;
#pragma unroll
        for (int jj = 0; jj < 4; ++jj) {
            float xv = acc[i][jj];
#pragma unroll
            for (int j = 0; j < 9; ++j) p[j] += xv * wh[jj][j];
        }
#pragma unroll
        for (int m = 1; m <= 16; m <<= 1)
#pragma unroll
            for (int j = 0; j < 9; ++j) p[j] += __shfl_xor(p[j], m);
        if (tx == 0) {
            int r = r0 + ty * 8 + i;
            float* o = out + (size_t)r * 9;
            o[0] = p[0] + bh[0];
            o[1] = p[1] + bh[1];
            o[2] = p[2] + bh[2];
            o[3] = expf(p[3] + bh[3]);
            o[4] = expf(p[4] + bh[4]);
            o[5] = expf(p[5] + bh[5]);
            o[6] = p[6] + bh[6];
            o[7] = p[7] + bh[7];
            o[8] = p[8] + bh[8];
        }
    }
}

// heads from cached fused (coalesced float4 reads)
__global__ __launch_bounds__(256) void heads_cached_kernel(const float* __restrict__ fused,
                                                           const float* __restrict__ ws,
                                                           float* __restrict__ out)
{
    const int tid = threadIdx.x;
    const int tx = tid & 31, ty = tid >> 5;
    const int r0 = blockIdx.x * 64;
    const int c0 = tx * 4;
    float acc[8][4];
#pragma unroll
    for (int i = 0; i < 8; ++i) {
        float4 v = *(const float4*)(fused + (size_t)(r0 + ty * 8 + i) * 128 + c0);
        acc[i][0] = v.x; acc[i][1] = v.y; acc[i][2] = v.z; acc[i][3] = v.w;
    }
    heads_epilogue(acc, ws, out, r0, tx, ty, c0);
}

// heads with GEMM recompute (fallback when ws too small)
__global__ __launch_bounds__(256) void heads_kernel(const float* __restrict__ A,
                                                    const float* __restrict__ Wf,
                                                    const int* __restrict__ bidx,
                                                    const float* __restrict__ ws,
                                                    float* __restrict__ out)
{
    __shared__ float lw[8192];
    const int tid = threadIdx.x;
    const int tx = tid & 31, ty = tid >> 5;
    const int r0 = blockIdx.x * 64;
    const int c0 = tx * 4;
    float acc[8][4];
#pragma unroll
    for (int i = 0; i < 8; ++i)
#pragma unroll
        for (int j = 0; j < 4; ++j) acc[i][j] = 0.f;

    GEMM_BODY(A, Wf, lw, acc, r0, tx, ty, c0)

    const float* T4 = ws + WS_T4;
#pragma unroll
    for (int i = 0; i < 8; ++i) {
        int r = r0 + ty * 8 + i;
        int b = bidx[r];
        float4 tv = *(const float4*)(T4 + b * 128 + c0);
        acc[i][0] += tv.x; acc[i][1] += tv.y; acc[i][2] += tv.z; acc[i][3] += tv.w;
    }
    heads_epilogue(acc, ws, out, r0, tx, ty, c0);
}

// ---------------- kth phase 1: sliced bound, atomicMin combine ----------------
__global__ __launch_bounds__(256) void bound_kernel(const float* __restrict__ p0,
                                                    const float* __restrict__ p1,
                                                    const float* __restrict__ boxes,
                                                    const int* __restrict__ glabels,
                                                    float* __restrict__ ws)
{
    const int j = blockIdx.x;
    const int slice = blockIdx.y, nslice = gridDim.y;
    const int tid = threadIdx.x;
    const float cx = boxes[j * 7 + 0], cy = boxes[j * 7 + 1], cz = boxes[j * 7 + 2];
    const int lvl = glabels[j];
    const float* pts = (lvl == 0) ? p0 : p1;
    const int M = (lvl == 0) ? NL0 : NL1;

    const int chunk = (M + nslice - 1) / nslice;
    const int i0 = slice * chunk;
    const int i1 = min(M, i0 + chunk);

    float m = FMAXV;
    for (int i = i0 + tid; i < i1; i += 256) {
        float dx = __fsub_rn(pts[i * 3 + 0], cx);
        float dy = __fsub_rn(pts[i * 3 + 1], cy);
        float dz = __fsub_rn(pts[i * 3 + 2], cz);
        float d2 = __fadd_rn(__fadd_rn(__fmul_rn(dx, dx), __fmul_rn(dy, dy)), __fmul_rn(dz, dz));
        m = fminf(m, d2);
    }

    __shared__ int wsum[4];
    unsigned lo = 0u, hi = __float_as_uint(FMAXV);
    for (int it = 0; it < 32; ++it) {
        unsigned mid = lo + ((hi - lo) >> 1);
        float midf = __uint_as_float(mid);
        unsigned long long b = __ballot(m <= midf);
        if ((tid & 63) == 0) wsum[tid >> 6] = __popcll(b);
        __syncthreads();
        int total = wsum[0] + wsum[1] + wsum[2] + wsum[3];
        if (total >= 33) hi = mid; else lo = mid + 1;
        __syncthreads();
    }
    if (tid == 0) atomicMin((unsigned*)(ws + WS_TB) + j, hi);
}

// ---------------- kth phase 2: collect ALL d2 <= T_j per box ----------------
__global__ __launch_bounds__(256) void collect_kernel(const float* __restrict__ p0,
                                                      const float* __restrict__ p1,
                                                      const float* __restrict__ boxes,
                                                      const int* __restrict__ glabels,
                                                      float* __restrict__ ws)
{
    const int j = blockIdx.x;
    const int slice = blockIdx.y, nslice = gridDim.y;
    const int tid = threadIdx.x;
    const float cx = boxes[j * 7 + 0], cy = boxes[j * 7 + 1], cz = boxes[j * 7 + 2];
    const int lvl = glabels[j];
    const float* pts = (lvl == 0) ? p0 : p1;
    const int M = (lvl == 0) ? NL0 : NL1;
    const float T = ws[WS_TB + j];
    int* cnt = (int*)(ws + WS_CNT) + j;
    float* cand = ws + WS_CAND + (size_t)j * CAP;

    const int chunk = (M + nslice - 1) / nslice;
    const int i0 = slice * chunk;
    const int i1 = min(M, i0 + chunk);
    for (int i = i0 + tid; i < i1; i += 256) {
        float dx = __fsub_rn(pts[i * 3 + 0], cx);
        float dy = __fsub_rn(pts[i * 3 + 1], cy);
        float dz = __fsub_rn(pts[i * 3 + 2], cz);
        float d2 = __fadd_rn(__fadd_rn(__fmul_rn(dx, dx), __fmul_rn(dy, dy)), __fmul_rn(dz, dz));
        if (d2 <= T) {
            int idx = atomicAdd(cnt, 1);
            if (idx < CAP) cand[idx] = d2;
        }
    }
}

// ---------------- kth phase 3: exact rank-33 over collected candidates ----------------
__global__ __launch_bounds__(256) void select_kernel(float* __restrict__ ws)
{
    const int j = blockIdx.x;
    const int tid = threadIdx.x;
    int n = ((int*)(ws + WS_CNT))[j];
    if (n > CAP) n = CAP;
    const float* cand = ws + WS_CAND + (size_t)j * CAP;
    float v[CAP / 256];
#pragma unroll
    for (int u = 0; u < CAP / 256; ++u) {
        int t = tid + u * 256;
        v[u] = (t < n) ? cand[t] : FMAXV;
    }
    __shared__ int wsum[4];
    unsigned lo = 0u, hi = __float_as_uint(FMAXV);
    for (int it = 0; it < 32; ++it) {
        unsigned mid = lo + ((hi - lo) >> 1);
        float midf = __uint_as_float(mid);
        int c = 0;
#pragma unroll
        for (int u = 0; u < CAP / 256; ++u) c += (v[u] <= midf) ? 1 : 0;
#pragma unroll
        for (int m = 32; m >= 1; m >>= 1) c += __shfl_xor(c, m);
        if ((tid & 63) == 0) wsum[tid >> 6] = c;
        __syncthreads();
        int total = wsum[0] + wsum[1] + wsum[2] + wsum[3];
        if (total >= 33) hi = mid; else lo = mid + 1;
        __syncthreads();
    }
    if (tid == 0) ws[WS_KTH + j] = __uint_as_float(hi);
}

// ---------------- assign: per point, raw argmin + gated argmin ----------------
__global__ __launch_bounds__(256) void assign_kernel(const float* __restrict__ p0,
                                                     const float* __restrict__ p1,
                                                     const float* __restrict__ boxes,
                                                     const int* __restrict__ glabels,
                                                     const float* __restrict__ ws,
                                                     float* __restrict__ out)
{
    __shared__ float cxa[128], cya[128], cza[128], kva[128];
    __shared__ int lva[128];
    int tid = threadIdx.x;
    if (tid < 128) {
        cxa[tid] = boxes[tid * 7 + 0];
        cya[tid] = boxes[tid * 7 + 1];
        cza[tid] = boxes[tid * 7 + 2];
        kva[tid] = ws[WS_KTH + tid];
        lva[tid] = glabels[tid];
    }
    __syncthreads();
    int i = blockIdx.x * 256 + tid;
    if (i >= N_TOT) return;
    int lvl = (i < NL0) ? 0 : 1;
    const float* p = (lvl == 0) ? (p0 + (size_t)i * 3) : (p1 + (size_t)(i - NL0) * 3);
    float px = p[0], py = p[1], pz = p[2];
    float bestA = FMAXV; int jA = 0;
    float bestG = FMAXV; int jG = -1;
    for (int j = 0; j < 128; ++j) {
        float dx = __fsub_rn(px, cxa[j]);
        float dy = __fsub_rn(py, cya[j]);
        float dz = __fsub_rn(pz, cza[j]);
        float d2 = __fadd_rn(__fadd_rn(__fmul_rn(dx, dx), __fmul_rn(dy, dy)), __fmul_rn(dz, dz));
        if (d2 < bestA) { bestA = d2; jA = j; }
        bool ok = (lva[j] == lvl) && (d2 < kva[j]);
        if (ok && d2 < bestG) { bestG = d2; jG = j; }
    }
    int res = (jG >= 0 && jG == jA) ? jG : -1;
    out[(size_t)9 * N_TOT + i] = (float)res;
}

extern "C" void kernel_launch(void* const* d_in, const int* in_sizes, int n_in,
                              void* d_out, int out_size, void* d_ws, size_t ws_size,
                              hipStream_t stream)
{
    const float* backbone = (const float*)d_in[0];
    const float* text     = (const float*)d_in[1];
    const float* Wf       = (const float*)d_in[2];
    const float* bfuse    = (const float*)d_in[3];
    const float* gamma    = (const float*)d_in[4];
    const float* beta     = (const float*)d_in[5];
    const float* Wbbox    = (const float*)d_in[6];
    const float* bbbox    = (const float*)d_in[7];
    const float* Wcls     = (const float*)d_in[8];
    const float* bcls     = (const float*)d_in[9];
    const float* p0       = (const float*)d_in[10];
    const float* p1       = (const float*)d_in[11];
    const int*   bidx     = (const int*)d_in[12];
    const int*   glab     = (const int*)d_in[13];
    const float* boxes    = (const float*)d_in[14];
    float* out = (float*)d_out;
    float* ws  = (float*)d_ws;

    const size_t need = ((size_t)WS_FUSED + (size_t)N_TOT * 128) * sizeof(float);
    const bool cache_fused = (ws_size >= need);
    float* fused = cache_fused ? (ws + WS_FUSED) : nullptr;

    prep_t4_kernel<<<1, 512, 0, stream>>>(text, Wf, bfuse, ws);
    prep_misc_kernel<<<1, 256, 0, stream>>>(Wbbox, bbbox, Wcls, bcls, ws);
    bound_kernel<<<dim3(NBOX, 8), 256, 0, stream>>>(p0, p1, boxes, glab, ws);
    collect_kernel<<<dim3(NBOX, 8), 256, 0, stream>>>(p0, p1, boxes, glab, ws);
    select_kernel<<<NBOX, 256, 0, stream>>>(ws);
    gemm_stats_kernel<<<N_TOT / 64, 256, 0, stream>>>(backbone, Wf, bidx, ws, fused);
    finalize_kernel<<<1, 128, 0, stream>>>(gamma, beta, ws, N_TOT);
    if (cache_fused)
        heads_cached_kernel<<<N_TOT / 64, 256, 0, stream>>>(fused, ws, out);
    else
        heads_kernel<<<N_TOT / 64, 256, 0, stream>>>(backbone, Wf, bidx, ws, out);
    assign_kernel<<<(N_TOT + 255) / 256, 256, 0, stream>>>(p0, p1, boxes, glab, ws, out);
}

// Round 6
// 381.505 us; speedup vs baseline: 1.1562x; 1.0728x over previous
//
#include <hip/hip_runtime.h>
#include <math.h>

#define N_TOT 160000
#define NL0   100000
#define NL1   60000
#define NBOX  128
#define FMAXV 1e8f
#define CAP   2048

// ws float offsets
#define WS_SUM   0      // 128
#define WS_SQ    128    // 128
#define WS_S     256    // 128
#define WS_T     384    // 128
#define WS_T4    512    // 512 -> 1024
#define WS_WH    1024   // 1152 [k][j] -> 2176
#define WS_BH    2176   // 9
#define WS_KTH   2192   // 128 -> 2320
#define WS_TB    2320   // 128 -> 2448
#define WS_CNT   2448   // 128 ints -> 2576
#define WS_WSZ   2576   // swizzled bf16 W: 16384 ushorts = 8192 floats -> 10768
#define WS_CAND  16384  // 128*2048 -> 278528
#define WS_FUSED 524288 // cached fused: bf16, 160000*128 ushorts

typedef __attribute__((ext_vector_type(8))) short bf16x8;
typedef __attribute__((ext_vector_type(4))) float f32x4;

__device__ __forceinline__ unsigned short f2bf(float f) {
    unsigned u = __float_as_uint(f);
    u += 0x7FFFu + ((u >> 16) & 1u);
    return (unsigned short)(u >> 16);
}

// ---------------- prep_t4: T4 = text@Wf[128:]+b_fuse ----------------
__global__ __launch_bounds__(512) void prep_t4_kernel(const float* __restrict__ text,
                                                      const float* __restrict__ Wf,
                                                      const float* __restrict__ bfuse,
                                                      float* __restrict__ ws)
{
    int idx = threadIdx.x;
    int b = idx >> 7, c = idx & 127;
    float acc = bfuse[c];
    for (int k = 0; k < 128; ++k)
        acc += text[b * 128 + k] * Wf[(128 + k) * 128 + c];
    ws[WS_T4 + idx] = acc;
}

// ---------------- prep_w: swizzle Wf[0:128] into bf16 MFMA-fragment order ----------------
// slot s = ks*512 + ct*64 + lane; frag element j: k = ks*32 + (lane>>4)*8 + j, col = ct*16 + (lane&15)
__global__ __launch_bounds__(256) void prep_w_kernel(const float* __restrict__ Wf,
                                                     float* __restrict__ ws)
{
    unsigned short* wsz = (unsigned short*)(ws + WS_WSZ);
    int t = threadIdx.x;
    for (int s = t; s < 2048; s += 256) {
        int lane = s & 63, ct = (s >> 6) & 7, ks = s >> 9;
        int q = lane >> 4, c = lane & 15;
        union { unsigned short u[8]; uint4 v; } pk;
#pragma unroll
        for (int j = 0; j < 8; ++j) {
            int k = ks * 32 + q * 8 + j;
            pk.u[j] = f2bf(Wf[k * 128 + ct * 16 + c]);
        }
        *(uint4*)(wsz + (size_t)s * 8) = pk.v;
    }
}

// ---------------- prep_misc: zero stats/counters, init TB, pack head weights ----------------
__global__ void prep_misc_kernel(const float* __restrict__ Wbbox, const float* __restrict__ bbbox,
                                 const float* __restrict__ Wcls, const float* __restrict__ bcls,
                                 float* __restrict__ ws)
{
    int t = threadIdx.x;
    if (t < 128) {
        ws[WS_SUM + t] = 0.f; ws[WS_SQ + t] = 0.f;
        ((int*)(ws + WS_CNT))[t] = 0;
        ((unsigned*)(ws + WS_TB))[t] = __float_as_uint(FMAXV);
    }
    for (int idx = t; idx < 1152; idx += 256) {
        int k = idx / 9, j = idx - k * 9;
        ws[WS_WH + idx] = (j < 7) ? Wbbox[k * 7 + j] : Wcls[k * 2 + (j - 7)];
    }
    if (t < 9) ws[WS_BH + t] = (t < 7) ? bbbox[t] : bcls[t - 7];
}

// ---------------- MFMA GEMM + stats + bf16 fused write ----------------
// block = 256 thr = 4 waves; wave w: rows [blk*64 + w*16, +16), cols 0..127 (8 ct tiles)
__global__ __launch_bounds__(256) void gemm_mfma_kernel(const float* __restrict__ A,
                                                        const int* __restrict__ bidx,
                                                        float* __restrict__ ws,
                                                        unsigned short* __restrict__ fused)
{
    __shared__ unsigned short lw[16384]; // 32 KB W fragments
    __shared__ float t4l[512];
    __shared__ float red_s[512], red_q[512];
    const int tid = threadIdx.x;
    const int lane = tid & 63, wid = tid >> 6;
    const int q = lane >> 4, c = lane & 15;
    const int r0 = blockIdx.x * 64 + wid * 16;

    {
        const float4* src = (const float4*)(ws + WS_WSZ);
        float4* dst = (float4*)lw;
        for (int i = tid; i < 2048; i += 256) dst[i] = src[i];
        const float4* t4s = (const float4*)(ws + WS_T4);
        float4* t4d = (float4*)t4l;
        if (tid < 128) t4d[tid] = t4s[tid];
    }
    __syncthreads();

    f32x4 acc[8];
#pragma unroll
    for (int ct = 0; ct < 8; ++ct) acc[ct] = (f32x4){0.f, 0.f, 0.f, 0.f};

    const float* abase = A + (size_t)(r0 + c) * 128 + q * 8;
    float4 a0 = *(const float4*)(abase);
    float4 a1 = *(const float4*)(abase + 4);
#pragma unroll
    for (int ks = 0; ks < 4; ++ks) {
        float4 n0, n1;
        if (ks < 3) {
            n0 = *(const float4*)(abase + (ks + 1) * 32);
            n1 = *(const float4*)(abase + (ks + 1) * 32 + 4);
        }
        union { unsigned short u[8]; bf16x8 v; } af;
        af.u[0] = f2bf(a0.x); af.u[1] = f2bf(a0.y); af.u[2] = f2bf(a0.z); af.u[3] = f2bf(a0.w);
        af.u[4] = f2bf(a1.x); af.u[5] = f2bf(a1.y); af.u[6] = f2bf(a1.z); af.u[7] = f2bf(a1.w);
#pragma unroll
        for (int ct = 0; ct < 8; ++ct) {
            bf16x8 bf = *(bf16x8*)(lw + ((size_t)(ks * 8 + ct) * 64 + lane) * 8);
            acc[ct] = __builtin_amdgcn_mfma_f32_16x16x32_bf16(af.v, bf, acc[ct], 0, 0, 0);
        }
        if (ks < 3) { a0 = n0; a1 = n1; }
    }

    // epilogue: + T4 (per-row batch table), C layout: row = r0 + q*4 + reg, col = ct*16 + c
    int rb[4];
#pragma unroll
    for (int rg = 0; rg < 4; ++rg) rb[rg] = bidx[r0 + q * 4 + rg];
#pragma unroll
    for (int ct = 0; ct < 8; ++ct) {
        int col = ct * 16 + c;
#pragma unroll
        for (int rg = 0; rg < 4; ++rg)
            acc[ct][rg] += t4l[rb[rg] * 128 + col];
    }
    // fused write (bf16)
#pragma unroll
    for (int ct = 0; ct < 8; ++ct) {
        int col = ct * 16 + c;
#pragma unroll
        for (int rg = 0; rg < 4; ++rg)
            fused[(size_t)(r0 + q * 4 + rg) * 128 + col] = f2bf(acc[ct][rg]);
    }
    // stats: reduce 4 rows locally, then across quads (lanes ^16, ^32)
#pragma unroll
    for (int ct = 0; ct < 8; ++ct) {
        float s = acc[ct][0] + acc[ct][1] + acc[ct][2] + acc[ct][3];
        float qq = acc[ct][0] * acc[ct][0] + acc[ct][1] * acc[ct][1] +
                   acc[ct][2] * acc[ct][2] + acc[ct][3] * acc[ct][3];
        s += __shfl_xor(s, 16); s += __shfl_xor(s, 32);
        qq += __shfl_xor(qq, 16); qq += __shfl_xor(qq, 32);
        if (lane < 16) {
            red_s[wid * 128 + ct * 16 + lane] = s;
            red_q[wid * 128 + ct * 16 + lane] = qq;
        }
    }
    __syncthreads();
    if (tid < 128) {
        float s = red_s[tid] + red_s[128 + tid] + red_s[256 + tid] + red_s[384 + tid];
        float qq = red_q[tid] + red_q[128 + tid] + red_q[256 + tid] + red_q[384 + tid];
        atomicAdd(ws + WS_SUM + tid, s);
        atomicAdd(ws + WS_SQ + tid, qq);
    }
}

__global__ void finalize_kernel(const float* __restrict__ gamma, const float* __restrict__ beta,
                                float* __restrict__ ws, int n)
{
    int c = threadIdx.x;
    if (c < 128) {
        float inv_n = 1.f / (float)n;
        float mu  = ws[WS_SUM + c] * inv_n;
        float var = ws[WS_SQ + c] * inv_n - mu * mu;
        float s = gamma[c] / sqrtf(var + 1e-5f);
        ws[WS_S + c] = s;
        ws[WS_T + c] = beta[c] - mu * s;
    }
}

// ---------------- heads from bf16 fused: LDS-staged, 4 threads/row ----------------
#define XPAD 136
__global__ __launch_bounds__(256) void heads_bf16_kernel(const unsigned short* __restrict__ fused,
                                                         const float* __restrict__ ws,
                                                         float* __restrict__ out)
{
    __shared__ unsigned short xs[64 * XPAD];
    __shared__ float whl[1152];
    __shared__ float sl[128], tl[128];
    __shared__ float bhl[9];
    __shared__ float part[64 * 4 * 9];
    const int tid = threadIdx.x;
    {
        int row = tid >> 2, ch = tid & 3;
        const float4* src = (const float4*)(fused + ((size_t)blockIdx.x * 64 + row) * 128 + ch * 32);
        float4* dst = (float4*)(xs + row * XPAD + ch * 32);
        dst[0] = src[0]; dst[1] = src[1]; dst[2] = src[2]; dst[3] = src[3];
    }
    for (int i = tid; i < 1152; i += 256) whl[i] = ws[WS_WH + i];
    if (tid < 128) { sl[tid] = ws[WS_S + tid]; tl[tid] = ws[WS_T + tid]; }
    if (tid < 9) bhl[tid] = ws[WS_BH + tid];
    __syncthreads();

    const int row = tid >> 2, qt = tid & 3;
    const unsigned short* xr = xs + row * XPAD + qt * 32;
    float p[9];
#pragma unroll
    for (int j = 0; j < 9; ++j) p[j] = 0.f;
    for (int cc = 0; cc < 32; ++cc) {
        int col = qt * 32 + cc;
        float xv = __uint_as_float(((unsigned)xr[cc]) << 16);
        xv = fmaxf(xv * sl[col] + tl[col], 0.f);
#pragma unroll
        for (int j = 0; j < 9; ++j) p[j] += xv * whl[col * 9 + j];
    }
    float* pp = part + (size_t)tid * 9;
#pragma unroll
    for (int j = 0; j < 9; ++j) pp[j] = p[j];
    __syncthreads();
    if (tid < 64) {
        float pr[9];
#pragma unroll
        for (int j = 0; j < 9; ++j)
            pr[j] = (part[(tid * 4 + 0) * 9 + j] + part[(tid * 4 + 1) * 9 + j]) +
                    (part[(tid * 4 + 2) * 9 + j] + part[(tid * 4 + 3) * 9 + j]) + bhl[j];
        float* o = out + ((size_t)blockIdx.x * 64 + tid) * 9;
        o[0] = pr[0]; o[1] = pr[1]; o[2] = pr[2];
        o[3] = expf(pr[3]); o[4] = expf(pr[4]); o[5] = expf(pr[5]);
        o[6] = pr[6]; o[7] = pr[7]; o[8] = pr[8];
    }
}

// ================= fallback path (ws too small): fp32 recompute =================
#define GEMM_BODY(A, Wf, lw, acc, r0, tx, ty, c0)                                        \
    for (int ph = 0; ph < 2; ++ph) {                                                     \
        const float4* wsrc = (const float4*)((Wf) + ph * 8192);                          \
        float4* wdst = (float4*)(lw);                                                    \
        for (int i = threadIdx.x; i < 2048; i += 256) wdst[i] = wsrc[i];                 \
        __syncthreads();                                                                 \
        for (int k4 = 0; k4 < 16; ++k4) {                                                \
            float4 a[8];                                                                 \
            _Pragma("unroll")                                                            \
            for (int i = 0; i < 8; ++i)                                                  \
                a[i] = *(const float4*)((A) + (size_t)((r0) + (ty) * 8 + i) * 128 + ph * 64 + k4 * 4); \
            _Pragma("unroll")                                                            \
            for (int kk = 0; kk < 4; ++kk) {                                             \
                float4 w = *(const float4*)((lw) + (k4 * 4 + kk) * 128 + (c0));          \
                _Pragma("unroll")                                                        \
                for (int i = 0; i < 8; ++i) {                                            \
                    float av = (kk == 0) ? a[i].x : (kk == 1) ? a[i].y : (kk == 2) ? a[i].z : a[i].w; \
                    acc[i][0] += av * w.x; acc[i][1] += av * w.y;                        \
                    acc[i][2] += av * w.z; acc[i][3] += av * w.w;                        \
                }                                                                        \
            }                                                                            \
        }                                                                                \
        __syncthreads();                                                                 \
    }

__global__ __launch_bounds__(256) void gemm_stats_kernel(const float* __restrict__ A,
                                                         const float* __restrict__ Wf,
                                                         const int* __restrict__ bidx,
                                                         float* __restrict__ ws)
{
    __shared__ float lw[8192];
    __shared__ float red[2048];
    const int tid = threadIdx.x;
    const int tx = tid & 31, ty = tid >> 5;
    const int r0 = blockIdx.x * 64;
    const int c0 = tx * 4;
    float acc[8][4];
#pragma unroll
    for (int i = 0; i < 8; ++i)
#pragma unroll
        for (int j = 0; j < 4; ++j) acc[i][j] = 0.f;
    GEMM_BODY(A, Wf, lw, acc, r0, tx, ty, c0)
    const float* T4 = ws + WS_T4;
#pragma unroll
    for (int i = 0; i < 8; ++i) {
        int r = r0 + ty * 8 + i;
        int b = bidx[r];
        float4 tv = *(const float4*)(T4 + b * 128 + c0);
        acc[i][0] += tv.x; acc[i][1] += tv.y; acc[i][2] += tv.z; acc[i][3] += tv.w;
    }
    {
        float s[4], qv[4];
#pragma unroll
        for (int j = 0; j < 4; ++j) {
            float a0 = 0.f, a1 = 0.f;
#pragma unroll
            for (int i = 0; i < 8; ++i) { float v = acc[i][j]; a0 += v; a1 += v * v; }
            s[j] = a0; qv[j] = a1;
        }
        *(float4*)(red + ty * 128 + c0)        = make_float4(s[0], s[1], s[2], s[3]);
        *(float4*)(red + 1024 + ty * 128 + c0) = make_float4(qv[0], qv[1], qv[2], qv[3]);
    }
    __syncthreads();
    if (tid < 128) {
        float s = 0.f, s2 = 0.f;
#pragma unroll
        for (int u = 0; u < 8; ++u) { s += red[u * 128 + tid]; s2 += red[1024 + u * 128 + tid]; }
        atomicAdd(ws + WS_SUM + tid, s);
        atomicAdd(ws + WS_SQ + tid, s2);
    }
}

__global__ __launch_bounds__(256) void heads_kernel(const float* __restrict__ A,
                                                    const float* __restrict__ Wf,
                                                    const int* __restrict__ bidx,
                                                    const float* __restrict__ ws,
                                                    float* __restrict__ out)
{
    __shared__ float lw[8192];
    const int tid = threadIdx.x;
    const int tx = tid & 31, ty = tid >> 5;
    const int r0 = blockIdx.x * 64;
    const int c0 = tx * 4;
    float acc[8][4];
#pragma unroll
    for (int i = 0; i < 8; ++i)
#pragma unroll
        for (int j = 0; j < 4; ++j) acc[i][j] = 0.f;
    GEMM_BODY(A, Wf, lw, acc, r0, tx, ty, c0)
    const float* T4 = ws + WS_T4;
#pragma unroll
    for (int i = 0; i < 8; ++i) {
        int r = r0 + ty * 8 + i;
        int b = bidx[r];
        float4 tv = *(const float4*)(T4 + b * 128 + c0);
        acc[i][0] += tv.x; acc[i][1] += tv.y; acc[i][2] += tv.z; acc[i][3] += tv.w;
    }
    float4 sc = *(const float4*)(ws + WS_S + c0);
    float4 tb = *(const float4*)(ws + WS_T + c0);
#pragma unroll
    for (int i = 0; i < 8; ++i) {
        acc[i][0] = fmaxf(acc[i][0] * sc.x + tb.x, 0.f);
        acc[i][1] = fmaxf(acc[i][1] * sc.y + tb.y, 0.f);
        acc[i][2] = fmaxf(acc[i][2] * sc.z + tb.z, 0.f);
        acc[i][3] = fmaxf(acc[i][3] * sc.w + tb.w, 0.f);
    }
    float wh[4][9];
#pragma unroll
    for (int jj = 0; jj < 4; ++jj)
#pragma unroll
        for (int j = 0; j < 9; ++j) wh[jj][j] = ws[WS_WH + (c0 + jj) * 9 + j];
    float bh[9];
#pragma unroll
    for (int j = 0; j < 9; ++j) bh[j] = ws[WS_BH + j];
#pragma unroll
    for (int i = 0; i < 8; ++i) {
        float p[9];
#pragma unroll
        for (int j = 0; j < 9; ++j) p[j] = 0.f;
#pragma unroll
        for (int jj = 0; jj < 4; ++jj) {
            float xv = acc[i][jj];
#pragma unroll
            for (int j = 0; j < 9; ++j) p[j] += xv * wh[jj][j];
        }
#pragma unroll
        for (int m = 1; m <= 16; m <<= 1)
#pragma unroll
            for (int j = 0; j < 9; ++j) p[j] += __shfl_xor(p[j], m);
        if (tx == 0) {
            int r = r0 + ty * 8 + i;
            float* o = out + (size_t)r * 9;
            o[0] = p[0] + bh[0]; o[1] = p[1] + bh[1]; o[2] = p[2] + bh[2];
            o[3] = expf(p[3] + bh[3]); o[4] = expf(p[4] + bh[4]); o[5] = expf(p[5] + bh[5]);
            o[6] = p[6] + bh[6]; o[7] = p[7] + bh[7]; o[8] = p[8] + bh[8];
        }
    }
}

// ---------------- kth phase 1: sliced bound, atomicMin combine ----------------
__global__ __launch_bounds__(256) void bound_kernel(const float* __restrict__ p0,
                                                    const float* __restrict__ p1,
                                                    const float* __restrict__ boxes,
                                                    const int* __restrict__ glabels,
                                                    float* __restrict__ ws)
{
    const int j = blockIdx.x;
    const int slice = blockIdx.y, nslice = gridDim.y;
    const int tid = threadIdx.x;
    const float cx = boxes[j * 7 + 0], cy = boxes[j * 7 + 1], cz = boxes[j * 7 + 2];
    const int lvl = glabels[j];
    const float* pts = (lvl == 0) ? p0 : p1;
    const int M = (lvl == 0) ? NL0 : NL1;

    const int chunk = (M + nslice - 1) / nslice;
    const int i0 = slice * chunk;
    const int i1 = min(M, i0 + chunk);

    float m = FMAXV;
    for (int i = i0 + tid; i < i1; i += 256) {
        float dx = __fsub_rn(pts[i * 3 + 0], cx);
        float dy = __fsub_rn(pts[i * 3 + 1], cy);
        float dz = __fsub_rn(pts[i * 3 + 2], cz);
        float d2 = __fadd_rn(__fadd_rn(__fmul_rn(dx, dx), __fmul_rn(dy, dy)), __fmul_rn(dz, dz));
        m = fminf(m, d2);
    }
    __shared__ int wsum[4];
    unsigned lo = 0u, hi = __float_as_uint(FMAXV);
    for (int it = 0; it < 32; ++it) {
        unsigned mid = lo + ((hi - lo) >> 1);
        float midf = __uint_as_float(mid);
        unsigned long long b = __ballot(m <= midf);
        if ((tid & 63) == 0) wsum[tid >> 6] = __popcll(b);
        __syncthreads();
        int total = wsum[0] + wsum[1] + wsum[2] + wsum[3];
        if (total >= 33) hi = mid; else lo = mid + 1;
        __syncthreads();
    }
    if (tid == 0) atomicMin((unsigned*)(ws + WS_TB) + j, hi);
}

// ---------------- kth phase 2: collect ALL d2 <= T_j per box ----------------
__global__ __launch_bounds__(256) void collect_kernel(const float* __restrict__ p0,
                                                      const float* __restrict__ p1,
                                                      const float* __restrict__ boxes,
                                                      const int* __restrict__ glabels,
                                                      float* __restrict__ ws)
{
    const int j = blockIdx.x;
    const int slice = blockIdx.y, nslice = gridDim.y;
    const int tid = threadIdx.x;
    const float cx = boxes[j * 7 + 0], cy = boxes[j * 7 + 1], cz = boxes[j * 7 + 2];
    const int lvl = glabels[j];
    const float* pts = (lvl == 0) ? p0 : p1;
    const int M = (lvl == 0) ? NL0 : NL1;
    const float T = ws[WS_TB + j];
    int* cnt = (int*)(ws + WS_CNT) + j;
    float* cand = ws + WS_CAND + (size_t)j * CAP;

    const int chunk = (M + nslice - 1) / nslice;
    const int i0 = slice * chunk;
    const int i1 = min(M, i0 + chunk);
    for (int i = i0 + tid; i < i1; i += 256) {
        float dx = __fsub_rn(pts[i * 3 + 0], cx);
        float dy = __fsub_rn(pts[i * 3 + 1], cy);
        float dz = __fsub_rn(pts[i * 3 + 2], cz);
        float d2 = __fadd_rn(__fadd_rn(__fmul_rn(dx, dx), __fmul_rn(dy, dy)), __fmul_rn(dz, dz));
        if (d2 <= T) {
            int idx = atomicAdd(cnt, 1);
            if (idx < CAP) cand[idx] = d2;
        }
    }
}

// ---------------- kth phase 3: exact rank-33 over collected candidates ----------------
__global__ __launch_bounds__(256) void select_kernel(float* __restrict__ ws)
{
    const int j = blockIdx.x;
    const int tid = threadIdx.x;
    int n = ((int*)(ws + WS_CNT))[j];
    if (n > CAP) n = CAP;
    const float* cand = ws + WS_CAND + (size_t)j * CAP;
    float v[CAP / 256];
#pragma unroll
    for (int u = 0; u < CAP / 256; ++u) {
        int t = tid + u * 256;
        v[u] = (t < n) ? cand[t] : FMAXV;
    }
    __shared__ int wsum[4];
    unsigned lo = 0u, hi = __float_as_uint(FMAXV);
    for (int it = 0; it < 32; ++it) {
        unsigned mid = lo + ((hi - lo) >> 1);
        float midf = __uint_as_float(mid);
        int c = 0;
#pragma unroll
        for (int u = 0; u < CAP / 256; ++u) c += (v[u] <= midf) ? 1 : 0;
#pragma unroll
        for (int m = 32; m >= 1; m >>= 1) c += __shfl_xor(c, m);
        if ((tid & 63) == 0) wsum[tid >> 6] = c;
        __syncthreads();
        int total = wsum[0] + wsum[1] + wsum[2] + wsum[3];
        if (total >= 33) hi = mid; else lo = mid + 1;
        __syncthreads();
    }
    if (tid == 0) ws[WS_KTH + j] = __uint_as_float(hi);
}

// ---------------- assign: per point, raw argmin + gated argmin ----------------
__global__ __launch_bounds__(256) void assign_kernel(const float* __restrict__ p0,
                                                     const float* __restrict__ p1,
                                                     const float* __restrict__ boxes,
                                                     const int* __restrict__ glabels,
                                                     const float* __restrict__ ws,
                                                     float* __restrict__ out)
{
    __shared__ float cxa[128], cya[128], cza[128], kva[128];
    __shared__ int lva[128];
    int tid = threadIdx.x;
    if (tid < 128) {
        cxa[tid] = boxes[tid * 7 + 0];
        cya[tid] = boxes[tid * 7 + 1];
        cza[tid] = boxes[tid * 7 + 2];
        kva[tid] = ws[WS_KTH + tid];
        lva[tid] = glabels[tid];
    }
    __syncthreads();
    int i = blockIdx.x * 256 + tid;
    if (i >= N_TOT) return;
    int lvl = (i < NL0) ? 0 : 1;
    const float* p = (lvl == 0) ? (p0 + (size_t)i * 3) : (p1 + (size_t)(i - NL0) * 3);
    float px = p[0], py = p[1], pz = p[2];
    float bestA = FMAXV; int jA = 0;
    float bestG = FMAXV; int jG = -1;
    for (int j = 0; j < 128; ++j) {
        float dx = __fsub_rn(px, cxa[j]);
        float dy = __fsub_rn(py, cya[j]);
        float dz = __fsub_rn(pz, cza[j]);
        float d2 = __fadd_rn(__fadd_rn(__fmul_rn(dx, dx), __fmul_rn(dy, dy)), __fmul_rn(dz, dz));
        if (d2 < bestA) { bestA = d2; jA = j; }
        bool ok = (lva[j] == lvl) && (d2 < kva[j]);
        if (ok && d2 < bestG) { bestG = d2; jG = j; }
    }
    int res = (jG >= 0 && jG == jA) ? jG : -1;
    out[(size_t)9 * N_TOT + i] = (float)res;
}

extern "C" void kernel_launch(void* const* d_in, const int* in_sizes, int n_in,
                              void* d_out, int out_size, void* d_ws, size_t ws_size,
                              hipStream_t stream)
{
    const float* backbone = (const float*)d_in[0];
    const float* text     = (const float*)d_in[1];
    const float* Wf       = (const float*)d_in[2];
    const float* bfuse    = (const float*)d_in[3];
    const float* gamma    = (const float*)d_in[4];
    const float* beta     = (const float*)d_in[5];
    const float* Wbbox    = (const float*)d_in[6];
    const float* bbbox    = (const float*)d_in[7];
    const float* Wcls     = (const float*)d_in[8];
    const float* bcls     = (const float*)d_in[9];
    const float* p0       = (const float*)d_in[10];
    const float* p1       = (const float*)d_in[11];
    const int*   bidx     = (const int*)d_in[12];
    const int*   glab     = (const int*)d_in[13];
    const float* boxes    = (const float*)d_in[14];
    float* out = (float*)d_out;
    float* ws  = (float*)d_ws;

    const size_t need = ((size_t)WS_FUSED + (size_t)N_TOT * 128) * sizeof(float);
    const bool cache_fused = (ws_size >= need);
    unsigned short* fused = (unsigned short*)(ws + WS_FUSED);

    prep_t4_kernel<<<1, 512, 0, stream>>>(text, Wf, bfuse, ws);
    prep_misc_kernel<<<1, 256, 0, stream>>>(Wbbox, bbbox, Wcls, bcls, ws);
    bound_kernel<<<dim3(NBOX, 8), 256, 0, stream>>>(p0, p1, boxes, glab, ws);
    collect_kernel<<<dim3(NBOX, 8), 256, 0, stream>>>(p0, p1, boxes, glab, ws);
    select_kernel<<<NBOX, 256, 0, stream>>>(ws);
    if (cache_fused) {
        prep_w_kernel<<<1, 256, 0, stream>>>(Wf, ws);
        gemm_mfma_kernel<<<N_TOT / 64, 256, 0, stream>>>(backbone, bidx, ws, fused);
        finalize_kernel<<<1, 128, 0, stream>>>(gamma, beta, ws, N_TOT);
        heads_bf16_kernel<<<N_TOT / 64, 256, 0, stream>>>(fused, ws, out);
    } else {
        gemm_stats_kernel<<<N_TOT / 64, 256, 0, stream>>>(backbone, Wf, bidx, ws);
        finalize_kernel<<<1, 128, 0, stream>>>(gamma, beta, ws, N_TOT);
        heads_kernel<<<N_TOT / 64, 256, 0, stream>>>(backbone, Wf, bidx, ws, out);
    }
    assign_kernel<<<(N_TOT + 255) / 256, 256, 0, stream>>>(p0, p1, boxes, glab, ws, out);
}

// Round 7
// 301.407 us; speedup vs baseline: 1.4635x; 1.2657x over previous
//
#include <hip/hip_runtime.h>
#include <math.h>

#define N_TOT 160000
#define NL0   100000
#define NL1   60000
#define NBOX  128
#define FMAXV 1e8f
#define CAP   2048

// ws float offsets
#define WS_SUM   0      // 128
#define WS_SQ    128    // 128
#define WS_S     256    // 128
#define WS_T     384    // 128
#define WS_T4    512    // 512 -> 1024
#define WS_WH    1024   // 1152 [k][j] -> 2176
#define WS_BH    2176   // 9
#define WS_KTH   2192   // 128 -> 2320
#define WS_CNT   2448   // 128 ints -> 2576
#define WS_TBS   2576   // 1024 (128 boxes x 8 slices) -> 3600
#define WS_WSZ   4096   // swizzled bf16 W: 16384 ushorts -> 12288
#define WS_CAND  16384  // 128*2048 -> 278528
#define WS_FUSED 524288 // cached fused: bf16, 160000*128 ushorts

typedef __attribute__((ext_vector_type(8))) short bf16x8;
typedef __attribute__((ext_vector_type(4))) float f32x4;

__device__ __forceinline__ unsigned short f2bf(float f) {
    unsigned u = __float_as_uint(f);
    u += 0x7FFFu + ((u >> 16) & 1u);
    return (unsigned short)(u >> 16);
}

// ---------------- fused prep + bound kernel ----------------
// blk 0: misc init; blk 1-2: T4; blk 3..1026: bound slices; blk 1027..1034: W swizzle
__global__ __launch_bounds__(256) void prep_bound_kernel(const float* __restrict__ text,
                                                         const float* __restrict__ Wf,
                                                         const float* __restrict__ bfuse,
                                                         const float* __restrict__ Wbbox,
                                                         const float* __restrict__ bbbox,
                                                         const float* __restrict__ Wcls,
                                                         const float* __restrict__ bcls,
                                                         const float* __restrict__ p0,
                                                         const float* __restrict__ p1,
                                                         const float* __restrict__ boxes,
                                                         const int* __restrict__ glabels,
                                                         float* __restrict__ ws)
{
    const int blk = blockIdx.x;
    const int tid = threadIdx.x;
    if (blk == 0) {
        if (tid < 128) {
            ws[WS_SUM + tid] = 0.f; ws[WS_SQ + tid] = 0.f;
            ((int*)(ws + WS_CNT))[tid] = 0;
        }
        for (int idx = tid; idx < 1152; idx += 256) {
            int k = idx / 9, j = idx - k * 9;
            ws[WS_WH + idx] = (j < 7) ? Wbbox[k * 7 + j] : Wcls[k * 2 + (j - 7)];
        }
        if (tid < 9) ws[WS_BH + tid] = (tid < 7) ? bbbox[tid] : bcls[tid - 7];
        return;
    }
    if (blk <= 2) {
        int idx = (blk - 1) * 256 + tid;   // 0..511
        int b = idx >> 7, c = idx & 127;
        float acc = bfuse[c];
        for (int k = 0; k < 128; ++k)
            acc += text[b * 128 + k] * Wf[(128 + k) * 128 + c];
        ws[WS_T4 + idx] = acc;
        return;
    }
    if (blk >= 1027) {
        // W swizzle into bf16 MFMA fragment order
        unsigned short* wsz = (unsigned short*)(ws + WS_WSZ);
        int s = (blk - 1027) * 256 + tid;  // 0..2047
        int lane = s & 63, ct = (s >> 6) & 7, ks = s >> 9;
        int q = lane >> 4, c = lane & 15;
        union { unsigned short u[8]; uint4 v; } pk;
#pragma unroll
        for (int j = 0; j < 8; ++j) {
            int k = ks * 32 + q * 8 + j;
            pk.u[j] = f2bf(Wf[k * 128 + ct * 16 + c]);
        }
        *(uint4*)(wsz + (size_t)s * 8) = pk.v;
        return;
    }
    // bound: blk-3 = j*8 + slice
    const int b = blk - 3;
    const int j = b >> 3, slice = b & 7;
    const float cx = boxes[j * 7 + 0], cy = boxes[j * 7 + 1], cz = boxes[j * 7 + 2];
    const int lvl = glabels[j];
    const float* pts = (lvl == 0) ? p0 : p1;
    const int M = (lvl == 0) ? NL0 : NL1;
    const int chunk = (M + 7) / 8;
    const int i0 = slice * chunk;
    const int i1 = min(M, i0 + chunk);
    float m = FMAXV;
    for (int i = i0 + tid; i < i1; i += 256) {
        float dx = __fsub_rn(pts[i * 3 + 0], cx);
        float dy = __fsub_rn(pts[i * 3 + 1], cy);
        float dz = __fsub_rn(pts[i * 3 + 2], cz);
        float d2 = __fadd_rn(__fadd_rn(__fmul_rn(dx, dx), __fmul_rn(dy, dy)), __fmul_rn(dz, dz));
        m = fminf(m, d2);
    }
    __shared__ int wsum[4];
    unsigned lo = 0u, hi = __float_as_uint(FMAXV);
    for (int it = 0; it < 16; ++it) {   // coarse: hi keeps count>=33 invariant -> valid upper bound
        unsigned mid = lo + ((hi - lo) >> 1);
        float midf = __uint_as_float(mid);
        unsigned long long bm = __ballot(m <= midf);
        if ((tid & 63) == 0) wsum[tid >> 6] = __popcll(bm);
        __syncthreads();
        int total = wsum[0] + wsum[1] + wsum[2] + wsum[3];
        if (total >= 33) hi = mid; else lo = mid + 1;
        __syncthreads();
    }
    if (tid == 0) ws[WS_TBS + j * 8 + slice] = __uint_as_float(hi);
}

// ---------------- collect: T = min of 8 slice bounds; gather all d2 <= T ----------------
__global__ __launch_bounds__(256) void collect_kernel(const float* __restrict__ p0,
                                                      const float* __restrict__ p1,
                                                      const float* __restrict__ boxes,
                                                      const int* __restrict__ glabels,
                                                      float* __restrict__ ws)
{
    const int j = blockIdx.x;
    const int slice = blockIdx.y, nslice = gridDim.y;
    const int tid = threadIdx.x;
    const float cx = boxes[j * 7 + 0], cy = boxes[j * 7 + 1], cz = boxes[j * 7 + 2];
    const int lvl = glabels[j];
    const float* pts = (lvl == 0) ? p0 : p1;
    const int M = (lvl == 0) ? NL0 : NL1;
    float T = ws[WS_TBS + j * 8];
#pragma unroll
    for (int s = 1; s < 8; ++s) T = fminf(T, ws[WS_TBS + j * 8 + s]);
    int* cnt = (int*)(ws + WS_CNT) + j;
    float* cand = ws + WS_CAND + (size_t)j * CAP;

    const int chunk = (M + nslice - 1) / nslice;
    const int i0 = slice * chunk;
    const int i1 = min(M, i0 + chunk);
    for (int i = i0 + tid; i < i1; i += 256) {
        float dx = __fsub_rn(pts[i * 3 + 0], cx);
        float dy = __fsub_rn(pts[i * 3 + 1], cy);
        float dz = __fsub_rn(pts[i * 3 + 2], cz);
        float d2 = __fadd_rn(__fadd_rn(__fmul_rn(dx, dx), __fmul_rn(dy, dy)), __fmul_rn(dz, dz));
        if (d2 <= T) {
            int idx = atomicAdd(cnt, 1);
            if (idx < CAP) cand[idx] = d2;
        }
    }
}

// ---------------- select: exact rank-33 over candidates ----------------
__global__ __launch_bounds__(256) void select_kernel(float* __restrict__ ws)
{
    const int j = blockIdx.x;
    const int tid = threadIdx.x;
    int n = ((int*)(ws + WS_CNT))[j];
    if (n > CAP) n = CAP;
    const float* cand = ws + WS_CAND + (size_t)j * CAP;
    float v[CAP / 256];
#pragma unroll
    for (int u = 0; u < CAP / 256; ++u) {
        int t = tid + u * 256;
        v[u] = (t < n) ? cand[t] : FMAXV;
    }
    __shared__ int wsum[4];
    unsigned lo = 0u, hi = __float_as_uint(FMAXV);
    for (int it = 0; it < 32; ++it) {
        unsigned mid = lo + ((hi - lo) >> 1);
        float midf = __uint_as_float(mid);
        int c = 0;
#pragma unroll
        for (int u = 0; u < CAP / 256; ++u) c += (v[u] <= midf) ? 1 : 0;
#pragma unroll
        for (int m = 32; m >= 1; m >>= 1) c += __shfl_xor(c, m);
        if ((tid & 63) == 0) wsum[tid >> 6] = c;
        __syncthreads();
        int total = wsum[0] + wsum[1] + wsum[2] + wsum[3];
        if (total >= 33) hi = mid; else lo = mid + 1;
        __syncthreads();
    }
    if (tid == 0) ws[WS_KTH + j] = __uint_as_float(hi);
}

// ---------------- MFMA GEMM v2: 128 rows/block, coalesced bf16 stores, reg stats ----------------
#define XROW 136
__global__ __launch_bounds__(256) void gemm_mfma_kernel(const float* __restrict__ A,
                                                        const int* __restrict__ bidx,
                                                        float* __restrict__ ws,
                                                        unsigned short* __restrict__ fused)
{
    __shared__ __align__(16) unsigned short lw[16384]; // 32 KB W fragments
    __shared__ float t4l[512];
    __shared__ __align__(16) unsigned short xt[4 * 16 * XROW]; // 17408 B, reused as red
    float* red_s = (float*)xt;
    float* red_q = ((float*)xt) + 512;
    const int tid = threadIdx.x;
    const int lane = tid & 63, wid = tid >> 6;
    const int q = lane >> 4, c = lane & 15;
    const int rb0 = blockIdx.x * 128 + wid * 16;

    {
        const float4* src = (const float4*)(ws + WS_WSZ);
        float4* dst = (float4*)lw;
        for (int i = tid; i < 2048; i += 256) dst[i] = src[i];
        if (tid < 128) ((float4*)t4l)[tid] = ((const float4*)(ws + WS_T4))[tid];
    }
    __syncthreads();

    float sacc[8], qacc[8];
#pragma unroll
    for (int ct = 0; ct < 8; ++ct) { sacc[ct] = 0.f; qacc[ct] = 0.f; }

    // prefetch all A for both row-tiles
    float4 av[2][8];
#pragma unroll
    for (int t = 0; t < 2; ++t) {
        const float* ar = A + (size_t)(rb0 + t * 64 + c) * 128 + q * 8;
#pragma unroll
        for (int u = 0; u < 8; ++u)
            av[t][u] = *(const float4*)(ar + (u >> 1) * 32 + (u & 1) * 4);
    }

    unsigned short* xw = xt + wid * (16 * XROW);

#pragma unroll
    for (int t = 0; t < 2; ++t) {
        const int r0 = rb0 + t * 64;
        f32x4 acc[8];
#pragma unroll
        for (int ct = 0; ct < 8; ++ct) acc[ct] = (f32x4){0.f, 0.f, 0.f, 0.f};
#pragma unroll
        for (int ks = 0; ks < 4; ++ks) {
            float4 a0 = av[t][ks * 2], a1 = av[t][ks * 2 + 1];
            union { unsigned short u[8]; bf16x8 v; } af;
            af.u[0] = f2bf(a0.x); af.u[1] = f2bf(a0.y); af.u[2] = f2bf(a0.z); af.u[3] = f2bf(a0.w);
            af.u[4] = f2bf(a1.x); af.u[5] = f2bf(a1.y); af.u[6] = f2bf(a1.z); af.u[7] = f2bf(a1.w);
#pragma unroll
            for (int ct = 0; ct < 8; ++ct) {
                bf16x8 bf = *(bf16x8*)(lw + ((size_t)(ks * 8 + ct) * 64 + lane) * 8);
                acc[ct] = __builtin_amdgcn_mfma_f32_16x16x32_bf16(af.v, bf, acc[ct], 0, 0, 0);
            }
        }
        int rbx[4];
#pragma unroll
        for (int rg = 0; rg < 4; ++rg) rbx[rg] = bidx[r0 + q * 4 + rg];
#pragma unroll
        for (int ct = 0; ct < 8; ++ct) {
            int col = ct * 16 + c;
#pragma unroll
            for (int rg = 0; rg < 4; ++rg) {
                float v = acc[ct][rg] + t4l[rbx[rg] * 128 + col];
                sacc[ct] += v; qacc[ct] += v * v;
                xw[(q * 4 + rg) * XROW + col] = f2bf(v);
            }
        }
        // coalesced store via wave-local LDS tile (compiler inserts lgkm waits)
#pragma unroll
        for (int k = 0; k < 4; ++k) {
            int row = k * 4 + (lane >> 4);
            int colu = (lane & 15) * 8;
            uint4 v = *(const uint4*)(xw + row * XROW + colu);
            *(uint4*)(fused + (size_t)(r0 + row) * 128 + colu) = v;
        }
    }
    __syncthreads();   // xt tile consumed; reuse as reduction buffer
#pragma unroll
    for (int ct = 0; ct < 8; ++ct) {
        float s = sacc[ct], qq = qacc[ct];
        s += __shfl_xor(s, 16); s += __shfl_xor(s, 32);
        qq += __shfl_xor(qq, 16); qq += __shfl_xor(qq, 32);
        if (lane < 16) {
            red_s[wid * 128 + ct * 16 + lane] = s;
            red_q[wid * 128 + ct * 16 + lane] = qq;
        }
    }
    __syncthreads();
    if (tid < 128) {
        float s = red_s[tid] + red_s[128 + tid] + red_s[256 + tid] + red_s[384 + tid];
        float qq = red_q[tid] + red_q[128 + tid] + red_q[256 + tid] + red_q[384 + tid];
        atomicAdd(ws + WS_SUM + tid, s);
        atomicAdd(ws + WS_SQ + tid, qq);
    }
}

__global__ void finalize_kernel(const float* __restrict__ gamma, const float* __restrict__ beta,
                                float* __restrict__ ws, int n)
{
    int c = threadIdx.x;
    if (c < 128) {
        float inv_n = 1.f / (float)n;
        float mu  = ws[WS_SUM + c] * inv_n;
        float var = ws[WS_SQ + c] * inv_n - mu * mu;
        float s = gamma[c] / sqrtf(var + 1e-5f);
        ws[WS_S + c] = s;
        ws[WS_T + c] = beta[c] - mu * s;
    }
}

// ---------------- combined heads + assign ----------------
// blocks [0,2500): heads (64 rows each); blocks [2500,3125): assign (256 pts each)
__global__ __launch_bounds__(256) void heads_assign_kernel(const unsigned short* __restrict__ fused,
                                                           const float* __restrict__ ws,
                                                           const float* __restrict__ p0,
                                                           const float* __restrict__ p1,
                                                           const float* __restrict__ boxes,
                                                           const int* __restrict__ glabels,
                                                           float* __restrict__ out)
{
    const int tid = threadIdx.x;
    if (blockIdx.x < 2500) {
        __shared__ float whT[1296];          // [j][qt] padded stride 36
        __shared__ float slp[144], tlp[144]; // qt-padded BN params
        __shared__ float bh[9];
        for (int idx = tid; idx < 1152; idx += 256) {
            int k = idx / 9, j = idx - k * 9;
            whT[(j * 4 + (k >> 5)) * 36 + (k & 31)] = ws[WS_WH + idx];
        }
        if (tid < 128) {
            slp[(tid >> 5) * 36 + (tid & 31)] = ws[WS_S + tid];
            tlp[(tid >> 5) * 36 + (tid & 31)] = ws[WS_T + tid];
        }
        if (tid < 9) bh[tid] = ws[WS_BH + tid];
        __syncthreads();

        const int row = blockIdx.x * 64 + (tid >> 2);
        const int qt = tid & 3;
        const unsigned short* xr = fused + (size_t)row * 128 + qt * 32;
        float4 xg[8];
#pragma unroll
        for (int g = 0; g < 8; ++g) {
            uint2 raw = *(const uint2*)(xr + g * 4);
            float4 sv = *(const float4*)(slp + qt * 36 + g * 4);
            float4 tv = *(const float4*)(tlp + qt * 36 + g * 4);
            float x0 = __uint_as_float((raw.x & 0xFFFFu) << 16);
            float x1 = __uint_as_float(raw.x & 0xFFFF0000u);
            float x2 = __uint_as_float((raw.y & 0xFFFFu) << 16);
            float x3 = __uint_as_float(raw.y & 0xFFFF0000u);
            xg[g].x = fmaxf(x0 * sv.x + tv.x, 0.f);
            xg[g].y = fmaxf(x1 * sv.y + tv.y, 0.f);
            xg[g].z = fmaxf(x2 * sv.z + tv.z, 0.f);
            xg[g].w = fmaxf(x3 * sv.w + tv.w, 0.f);
        }
        float p[9];
#pragma unroll
        for (int j = 0; j < 9; ++j) {
            const float* wp = whT + (j * 4 + qt) * 36;
            float a = 0.f;
#pragma unroll
            for (int g = 0; g < 8; ++g) {
                float4 w = *(const float4*)(wp + g * 4);
                a += xg[g].x * w.x + xg[g].y * w.y + xg[g].z * w.z + xg[g].w * w.w;
            }
            p[j] = a;
        }
#pragma unroll
        for (int j = 0; j < 9; ++j) { p[j] += __shfl_xor(p[j], 1); p[j] += __shfl_xor(p[j], 2); }
        if (qt == 0) {
            float* o = out + (size_t)row * 9;
            o[0] = p[0] + bh[0]; o[1] = p[1] + bh[1]; o[2] = p[2] + bh[2];
            o[3] = expf(p[3] + bh[3]); o[4] = expf(p[4] + bh[4]); o[5] = expf(p[5] + bh[5]);
            o[6] = p[6] + bh[6]; o[7] = p[7] + bh[7]; o[8] = p[8] + bh[8];
        }
        return;
    }
    // ---- assign part ----
    __shared__ float cxa[128], cya[128], cza[128], kva[128];
    __shared__ int lva[128];
    if (tid < 128) {
        cxa[tid] = boxes[tid * 7 + 0];
        cya[tid] = boxes[tid * 7 + 1];
        cza[tid] = boxes[tid * 7 + 2];
        kva[tid] = ws[WS_KTH + tid];
        lva[tid] = glabels[tid];
    }
    __syncthreads();
    int i = (blockIdx.x - 2500) * 256 + tid;
    if (i >= N_TOT) return;
    int lvl = (i < NL0) ? 0 : 1;
    const float* p = (lvl == 0) ? (p0 + (size_t)i * 3) : (p1 + (size_t)(i - NL0) * 3);
    float px = p[0], py = p[1], pz = p[2];
    float bestA = FMAXV; int jA = 0;
    float bestG = FMAXV; int jG = -1;
    for (int j = 0; j < 128; ++j) {
        float dx = __fsub_rn(px, cxa[j]);
        float dy = __fsub_rn(py, cya[j]);
        float dz = __fsub_rn(pz, cza[j]);
        float d2 = __fadd_rn(__fadd_rn(__fmul_rn(dx, dx), __fmul_rn(dy, dy)), __fmul_rn(dz, dz));
        if (d2 < bestA) { bestA = d2; jA = j; }
        bool ok = (lva[j] == lvl) && (d2 < kva[j]);
        if (ok && d2 < bestG) { bestG = d2; jG = j; }
    }
    int res = (jG >= 0 && jG == jA) ? jG : -1;
    out[(size_t)9 * N_TOT + i] = (float)res;
}

// ================= fallback path (ws too small): fp32 recompute =================
#define GEMM_BODY(A, Wf, lw, acc, r0, tx, ty, c0)                                        \
    for (int ph = 0; ph < 2; ++ph) {                                                     \
        const float4* wsrc = (const float4*)((Wf) + ph * 8192);                          \
        float4* wdst = (float4*)(lw);                                                    \
        for (int i = threadIdx.x; i < 2048; i += 256) wdst[i] = wsrc[i];                 \
        __syncthreads();                                                                 \
        for (int k4 = 0; k4 < 16; ++k4) {                                                \
            float4 a[8];                                                                 \
            _Pragma("unroll")                                                            \
            for (int i = 0; i < 8; ++i)                                                  \
                a[i] = *(const float4*)((A) + (size_t)((r0) + (ty) * 8 + i) * 128 + ph * 64 + k4 * 4); \
            _Pragma("unroll")                                                            \
            for (int kk = 0; kk < 4; ++kk) {                                             \
                float4 w = *(const float4*)((lw) + (k4 * 4 + kk) * 128 + (c0));          \
                _Pragma("unroll")                                                        \
                for (int i = 0; i < 8; ++i) {                                            \
                    float av = (kk == 0) ? a[i].x : (kk == 1) ? a[i].y : (kk == 2) ? a[i].z : a[i].w; \
                    acc[i][0] += av * w.x; acc[i][1] += av * w.y;                        \
                    acc[i][2] += av * w.z; acc[i][3] += av * w.w;                        \
                }                                                                        \
            }                                                                            \
        }                                                                                \
        __syncthreads();                                                                 \
    }

__global__ __launch_bounds__(256) void gemm_stats_kernel(const float* __restrict__ A,
                                                         const float* __restrict__ Wf,
                                                         const int* __restrict__ bidx,
                                                         float* __restrict__ ws)
{
    __shared__ float lw[8192];
    __shared__ float red[2048];
    const int tid = threadIdx.x;
    const int tx = tid & 31, ty = tid >> 5;
    const int r0 = blockIdx.x * 64;
    const int c0 = tx * 4;
    float acc[8][4];
#pragma unroll
    for (int i = 0; i < 8; ++i)
#pragma unroll
        for (int j = 0; j < 4; ++j) acc[i][j] = 0.f;
    GEMM_BODY(A, Wf, lw, acc, r0, tx, ty, c0)
    const float* T4 = ws + WS_T4;
#pragma unroll
    for (int i = 0; i < 8; ++i) {
        int r = r0 + ty * 8 + i;
        int b = bidx[r];
        float4 tv = *(const float4*)(T4 + b * 128 + c0);
        acc[i][0] += tv.x; acc[i][1] += tv.y; acc[i][2] += tv.z; acc[i][3] += tv.w;
    }
    {
        float s[4], qv[4];
#pragma unroll
        for (int j = 0; j < 4; ++j) {
            float a0 = 0.f, a1 = 0.f;
#pragma unroll
            for (int i = 0; i < 8; ++i) { float v = acc[i][j]; a0 += v; a1 += v * v; }
            s[j] = a0; qv[j] = a1;
        }
        *(float4*)(red + ty * 128 + c0)        = make_float4(s[0], s[1], s[2], s[3]);
        *(float4*)(red + 1024 + ty * 128 + c0) = make_float4(qv[0], qv[1], qv[2], qv[3]);
    }
    __syncthreads();
    if (tid < 128) {
        float s = 0.f, s2 = 0.f;
#pragma unroll
        for (int u = 0; u < 8; ++u) { s += red[u * 128 + tid]; s2 += red[1024 + u * 128 + tid]; }
        atomicAdd(ws + WS_SUM + tid, s);
        atomicAdd(ws + WS_SQ + tid, s2);
    }
}

__global__ __launch_bounds__(256) void heads_kernel(const float* __restrict__ A,
                                                    const float* __restrict__ Wf,
                                                    const int* __restrict__ bidx,
                                                    const float* __restrict__ ws,
                                                    float* __restrict__ out)
{
    __shared__ float lw[8192];
    const int tid = threadIdx.x;
    const int tx = tid & 31, ty = tid >> 5;
    const int r0 = blockIdx.x * 64;
    const int c0 = tx * 4;
    float acc[8][4];
#pragma unroll
    for (int i = 0; i < 8; ++i)
#pragma unroll
        for (int j = 0; j < 4; ++j) acc[i][j] = 0.f;
    GEMM_BODY(A, Wf, lw, acc, r0, tx, ty, c0)
    const float* T4 = ws + WS_T4;
#pragma unroll
    for (int i = 0; i < 8; ++i) {
        int r = r0 + ty * 8 + i;
        int b = bidx[r];
        float4 tv = *(const float4*)(T4 + b * 128 + c0);
        acc[i][0] += tv.x; acc[i][1] += tv.y; acc[i][2] += tv.z; acc[i][3] += tv.w;
    }
    float4 sc = *(const float4*)(ws + WS_S + c0);
    float4 tb = *(const float4*)(ws + WS_T + c0);
#pragma unroll
    for (int i = 0; i < 8; ++i) {
        acc[i][0] = fmaxf(acc[i][0] * sc.x + tb.x, 0.f);
        acc[i][1] = fmaxf(acc[i][1] * sc.y + tb.y, 0.f);
        acc[i][2] = fmaxf(acc[i][2] * sc.z + tb.z, 0.f);
        acc[i][3] = fmaxf(acc[i][3] * sc.w + tb.w, 0.f);
    }
    float wh[4][9];
#pragma unroll
    for (int jj = 0; jj < 4; ++jj)
#pragma unroll
        for (int j = 0; j < 9; ++j) wh[jj][j] = ws[WS_WH + (c0 + jj) * 9 + j];
    float bh[9];
#pragma unroll
    for (int j = 0; j < 9; ++j) bh[j] = ws[WS_BH + j];
#pragma unroll
    for (int i = 0; i < 8; ++i) {
        float p[9];
#pragma unroll
        for (int j = 0; j < 9; ++j) p[j] = 0.f;
#pragma unroll
        for (int jj = 0; jj < 4; ++jj) {
            float xv = acc[i][jj];
#pragma unroll
            for (int j = 0; j < 9; ++j) p[j] += xv * wh[jj][j];
        }
#pragma unroll
        for (int m = 1; m <= 16; m <<= 1)
#pragma unroll
            for (int j = 0; j < 9; ++j) p[j] += __shfl_xor(p[j], m);
        if (tx == 0) {
            int r = r0 + ty * 8 + i;
            float* o = out + (size_t)r * 9;
            o[0] = p[0] + bh[0]; o[1] = p[1] + bh[1]; o[2] = p[2] + bh[2];
            o[3] = expf(p[3] + bh[3]); o[4] = expf(p[4] + bh[4]); o[5] = expf(p[5] + bh[5]);
            o[6] = p[6] + bh[6]; o[7] = p[7] + bh[7]; o[8] = p[8] + bh[8];
        }
    }
}

__global__ __launch_bounds__(256) void assign_kernel(const float* __restrict__ p0,
                                                     const float* __restrict__ p1,
                                                     const float* __restrict__ boxes,
                                                     const int* __restrict__ glabels,
                                                     const float* __restrict__ ws,
                                                     float* __restrict__ out)
{
    __shared__ float cxa[128], cya[128], cza[128], kva[128];
    __shared__ int lva[128];
    int tid = threadIdx.x;
    if (tid < 128) {
        cxa[tid] = boxes[tid * 7 + 0];
        cya[tid] = boxes[tid * 7 + 1];
        cza[tid] = boxes[tid * 7 + 2];
        kva[tid] = ws[WS_KTH + tid];
        lva[tid] = glabels[tid];
    }
    __syncthreads();
    int i = blockIdx.x * 256 + tid;
    if (i >= N_TOT) return;
    int lvl = (i < NL0) ? 0 : 1;
    const float* p = (lvl == 0) ? (p0 + (size_t)i * 3) : (p1 + (size_t)(i - NL0) * 3);
    float px = p[0], py = p[1], pz = p[2];
    float bestA = FMAXV; int jA = 0;
    float bestG = FMAXV; int jG = -1;
    for (int j = 0; j < 128; ++j) {
        float dx = __fsub_rn(px, cxa[j]);
        float dy = __fsub_rn(py, cya[j]);
        float dz = __fsub_rn(pz, cza[j]);
        float d2 = __fadd_rn(__fadd_rn(__fmul_rn(dx, dx), __fmul_rn(dy, dy)), __fmul_rn(dz, dz));
        if (d2 < bestA) { bestA = d2; jA = j; }
        bool ok = (lva[j] == lvl) && (d2 < kva[j]);
        if (ok && d2 < bestG) { bestG = d2; jG = j; }
    }
    int res = (jG >= 0 && jG == jA) ? jG : -1;
    out[(size_t)9 * N_TOT + i] = (float)res;
}

extern "C" void kernel_launch(void* const* d_in, const int* in_sizes, int n_in,
                              void* d_out, int out_size, void* d_ws, size_t ws_size,
                              hipStream_t stream)
{
    const float* backbone = (const float*)d_in[0];
    const float* text     = (const float*)d_in[1];
    const float* Wf       = (const float*)d_in[2];
    const float* bfuse    = (const float*)d_in[3];
    const float* gamma    = (const float*)d_in[4];
    const float* beta     = (const float*)d_in[5];
    const float* Wbbox    = (const float*)d_in[6];
    const float* bbbox    = (const float*)d_in[7];
    const float* Wcls     = (const float*)d_in[8];
    const float* bcls     = (const float*)d_in[9];
    const float* p0       = (const float*)d_in[10];
    const float* p1       = (const float*)d_in[11];
    const int*   bidx     = (const int*)d_in[12];
    const int*   glab     = (const int*)d_in[13];
    const float* boxes    = (const float*)d_in[14];
    float* out = (float*)d_out;
    float* ws  = (float*)d_ws;

    const size_t need = ((size_t)WS_FUSED + (size_t)N_TOT * 128) * sizeof(float);
    const bool cache_fused = (ws_size >= need);
    unsigned short* fused = (unsigned short*)(ws + WS_FUSED);

    prep_bound_kernel<<<1035, 256, 0, stream>>>(text, Wf, bfuse, Wbbox, bbbox, Wcls, bcls,
                                                p0, p1, boxes, glab, ws);
    collect_kernel<<<dim3(NBOX, 8), 256, 0, stream>>>(p0, p1, boxes, glab, ws);
    select_kernel<<<NBOX, 256, 0, stream>>>(ws);
    if (cache_fused) {
        gemm_mfma_kernel<<<N_TOT / 128, 256, 0, stream>>>(backbone, bidx, ws, fused);
        finalize_kernel<<<1, 128, 0, stream>>>(gamma, beta, ws, N_TOT);
        heads_assign_kernel<<<2500 + (N_TOT + 255) / 256, 256, 0, stream>>>(
            fused, ws, p0, p1, boxes, glab, out);
    } else {
        gemm_stats_kernel<<<N_TOT / 64, 256, 0, stream>>>(backbone, Wf, bidx, ws);
        finalize_kernel<<<1, 128, 0, stream>>>(gamma, beta, ws, N_TOT);
        heads_kernel<<<N_TOT / 64, 256, 0, stream>>>(backbone, Wf, bidx, ws, out);
        assign_kernel<<<(N_TOT + 255) / 256, 256, 0, stream>>>(p0, p1, boxes, glab, ws, out);
    }
}